// Round 1
// baseline (451.327 us; speedup 1.0000x reference)
//
#include <hip/hip_runtime.h>
#include <math.h>

// Problem constants: B=16, C=256, H=W=64, N=4096, GROUPS=16 (cg=16), HEADS=8 (ch=32)

__device__ __forceinline__ float sigmoidf_(float v) { return 1.0f / (1.0f + __expf(-v)); }

// ---------------------------------------------------------------------------
// Generic 64x64-tile fp32 GEMM, 256 threads, 4x4 micro-tile, BK=32.
// BT:  C[m][n] = sum_k A[m][k] * B[n][k]   (A,B row-major, B used transposed)
// !BT: C[m][n] = sum_k A[m][k] * B[k][n]
// EPI: y = X*sigmoid(WP) + acc fused epilogue (Out kernel), N must be 4096.
// LDS layout: tiles stored K-major [kk][m] so fragment reads are ds_read_b128.
// ---------------------------------------------------------------------------
template <bool BT, bool EPI>
__global__ __launch_bounds__(256) void gemm64(
    const float* __restrict__ A, const float* __restrict__ B, float* __restrict__ C,
    int M, int N, int K, long sA, long sB, long sC,
    const float* __restrict__ X, const float* __restrict__ WP)
{
    __shared__ float As[32][68];
    __shared__ float Bs[32][68];
    const int b = blockIdx.z;
    const float* Ab = A + (long)b * sA;
    const float* Bb = B + (long)b * sB;
    float* Cb = C + (long)b * sC;
    const int t = threadIdx.x;
    const int tx = t & 15, ty = t >> 4;
    const int m0 = blockIdx.y * 64, n0 = blockIdx.x * 64;

    float acc[4][4] = {};

    for (int k0 = 0; k0 < K; k0 += 32) {
        __syncthreads();
        // A tile (64 rows x 32 k), scatter to K-major LDS
        #pragma unroll
        for (int f0 = 0; f0 < 512; f0 += 256) {
            const int f = f0 + t;
            const int row = f >> 3, c4 = f & 7;
            const float4 v = *(const float4*)(Ab + (long)(m0 + row) * K + k0 + c4 * 4);
            As[c4 * 4 + 0][row] = v.x;
            As[c4 * 4 + 1][row] = v.y;
            As[c4 * 4 + 2][row] = v.z;
            As[c4 * 4 + 3][row] = v.w;
        }
        if (BT) {
            #pragma unroll
            for (int f0 = 0; f0 < 512; f0 += 256) {
                const int f = f0 + t;
                const int row = f >> 3, c4 = f & 7;
                const float4 v = *(const float4*)(Bb + (long)(n0 + row) * K + k0 + c4 * 4);
                Bs[c4 * 4 + 0][row] = v.x;
                Bs[c4 * 4 + 1][row] = v.y;
                Bs[c4 * 4 + 2][row] = v.z;
                Bs[c4 * 4 + 3][row] = v.w;
            }
        } else {
            #pragma unroll
            for (int f0 = 0; f0 < 512; f0 += 256) {
                const int f = f0 + t;
                const int kk = f >> 4, c4 = f & 15;
                *(float4*)&Bs[kk][c4 * 4] =
                    *(const float4*)(Bb + (long)(k0 + kk) * N + n0 + c4 * 4);
            }
        }
        __syncthreads();
        #pragma unroll
        for (int kk = 0; kk < 32; ++kk) {
            const float4 av = *(const float4*)&As[kk][ty * 4];
            const float4 bv = *(const float4*)&Bs[kk][tx * 4];
            const float a0 = av.x, a1 = av.y, a2 = av.z, a3 = av.w;
            const float b0 = bv.x, b1 = bv.y, b2 = bv.z, b3 = bv.w;
            acc[0][0] += a0 * b0; acc[0][1] += a0 * b1; acc[0][2] += a0 * b2; acc[0][3] += a0 * b3;
            acc[1][0] += a1 * b0; acc[1][1] += a1 * b1; acc[1][2] += a1 * b2; acc[1][3] += a1 * b3;
            acc[2][0] += a2 * b0; acc[2][1] += a2 * b1; acc[2][2] += a2 * b2; acc[2][3] += a2 * b3;
            acc[3][0] += a3 * b0; acc[3][1] += a3 * b1; acc[3][2] += a3 * b2; acc[3][3] += a3 * b3;
        }
    }

    if (EPI) {
        #pragma unroll
        for (int i = 0; i < 4; ++i) {
            const int c = m0 + ty * 4 + i;
            const long nidx = n0 + tx * 4;
            const float4 xv = *(const float4*)(X + ((long)b * 256 + c) * 4096 + nidx);
            const float4 wv = *(const float4*)(WP + ((long)b * 16 + (c >> 4)) * 4096 + nidx);
            float4 o;
            o.x = xv.x * sigmoidf_(wv.x) + acc[i][0];
            o.y = xv.y * sigmoidf_(wv.y) + acc[i][1];
            o.z = xv.z * sigmoidf_(wv.z) + acc[i][2];
            o.w = xv.w * sigmoidf_(wv.w) + acc[i][3];
            *(float4*)(Cb + (long)c * N + nidx) = o;
        }
    } else {
        #pragma unroll
        for (int i = 0; i < 4; ++i) {
            const float4 o = make_float4(acc[i][0], acc[i][1], acc[i][2], acc[i][3]);
            *(float4*)(Cb + (long)(m0 + ty * 4 + i) * N + n0 + tx * 4) = o;
        }
    }
}

// ---------------------------------------------------------------------------
// Per-(b,h) attention in Gram space. T = w_qkv @ G (768x256 per batch).
// qk[c][d]  = T[h32+c] . Wk_d            (Wk_d = w_qkv row 256+h32+d)
// |q_c|^2   = T[h32+c] . Wq_c
// |k_d|^2   = T[256+h32+d] . Wk_d
// M[h32+c]  = sum_d attn[c][d] * Wv_d    (Wv_d = w_qkv row 512+h32+d)
// ---------------------------------------------------------------------------
__global__ __launch_bounds__(256) void attn_kernel(
    const float* __restrict__ T, const float* __restrict__ wqkv,
    const float* __restrict__ temp, float* __restrict__ Mout)
{
    const int bh = blockIdx.x;
    const int b = bh >> 3, h = bh & 7;
    const int t = threadIdx.x;
    __shared__ float Tq[32][260];   // q-part rows of T
    __shared__ float qk[32][33];    // logits, overwritten by attn weights
    __shared__ float qn[32], kn[32];
    const float* Tb = T + (long)b * 768 * 256;

    for (int f = t; f < 32 * 64; f += 256) {
        const int r = f >> 6, c4 = f & 63;
        *(float4*)&Tq[r][c4 * 4] = *(const float4*)(Tb + (long)(h * 32 + r) * 256 + c4 * 4);
    }
    __syncthreads();

    // norms (wave 0: lanes 0-31 -> q norms, 32-63 -> k norms)
    if (t < 32) {
        float s = 0.f;
        const float* wq = wqkv + (long)(h * 32 + t) * 256;
        #pragma unroll 4
        for (int k = 0; k < 256; k += 4) {
            const float4 a = *(const float4*)&Tq[t][k];
            const float4 w = *(const float4*)(wq + k);
            s += a.x * w.x + a.y * w.y + a.z * w.z + a.w * w.w;
        }
        qn[t] = fmaxf(sqrtf(s), 1e-12f);
    } else if (t < 64) {
        const int d = t - 32;
        float s = 0.f;
        const float* tk = Tb + (long)(256 + h * 32 + d) * 256;
        const float* wk = wqkv + (long)(256 + h * 32 + d) * 256;
        #pragma unroll 4
        for (int k = 0; k < 256; k += 4) {
            const float4 a = *(const float4*)(tk + k);
            const float4 w = *(const float4*)(wk + k);
            s += a.x * w.x + a.y * w.y + a.z * w.z + a.w * w.w;
        }
        kn[d] = fmaxf(sqrtf(s), 1e-12f);
    }

    // qk logits: thread handles (c, d0..d0+3)
    {
        const int c = t >> 3, d0 = (t & 7) * 4;
        float s0 = 0, s1 = 0, s2 = 0, s3 = 0;
        const float* wk0 = wqkv + (long)(256 + h * 32 + d0) * 256;
        #pragma unroll 4
        for (int k = 0; k < 256; k += 4) {
            const float4 a = *(const float4*)&Tq[c][k];
            const float4 w0 = *(const float4*)(wk0 + k);
            const float4 w1 = *(const float4*)(wk0 + 256 + k);
            const float4 w2 = *(const float4*)(wk0 + 512 + k);
            const float4 w3 = *(const float4*)(wk0 + 768 + k);
            s0 += a.x * w0.x + a.y * w0.y + a.z * w0.z + a.w * w0.w;
            s1 += a.x * w1.x + a.y * w1.y + a.z * w1.z + a.w * w1.w;
            s2 += a.x * w2.x + a.y * w2.y + a.z * w2.z + a.w * w2.w;
            s3 += a.x * w3.x + a.y * w3.y + a.z * w3.z + a.w * w3.w;
        }
        qk[c][d0 + 0] = s0;
        qk[c][d0 + 1] = s1;
        qk[c][d0 + 2] = s2;
        qk[c][d0 + 3] = s3;
    }
    __syncthreads();

    // softmax per row (32 lanes)
    if (t < 32) {
        const float tscale = temp[h];
        const float qin = tscale / qn[t];
        float lg[32];
        float mx = -1e30f;
        #pragma unroll
        for (int d = 0; d < 32; ++d) {
            const float l = qk[t][d] * qin / kn[d];
            lg[d] = l;
            mx = fmaxf(mx, l);
        }
        float s = 0.f;
        #pragma unroll
        for (int d = 0; d < 32; ++d) { lg[d] = __expf(lg[d] - mx); s += lg[d]; }
        const float inv = 1.0f / s;
        #pragma unroll
        for (int d = 0; d < 32; ++d) qk[t][d] = lg[d] * inv;
    }
    __syncthreads();

    // M rows: thread owns column i=t, accumulates all 32 c simultaneously
    float accm[32];
    #pragma unroll
    for (int c = 0; c < 32; ++c) accm[c] = 0.f;
    const float* wv = wqkv + (long)(512 + h * 32) * 256 + t;
    #pragma unroll 4
    for (int d = 0; d < 32; ++d) {
        const float wvv = wv[(long)d * 256];
        #pragma unroll
        for (int c = 0; c < 32; ++c) accm[c] += qk[c][d] * wvv;
    }
    float* mo = Mout + (long)b * 256 * 256 + (long)(h * 32) * 256 + t;
    #pragma unroll
    for (int c = 0; c < 32; ++c) mo[(long)c * 256] = accm[c];
}

// ---------------------------------------------------------------------------
// W2[b][g][i] = sum_c softmax(gn_b)[c] * P[b][16g+c][i]
// (x11 == softmax(gn_b) analytically: GN-normalized mean is exactly gn_b)
// ---------------------------------------------------------------------------
__global__ __launch_bounds__(256) void w2_kernel(
    const float* __restrict__ P, const float* __restrict__ gnb, float* __restrict__ W2)
{
    const int b = blockIdx.x, i = threadIdx.x;
    float e[16];
    float mx = -1e30f;
    #pragma unroll
    for (int c = 0; c < 16; ++c) mx = fmaxf(mx, gnb[c]);
    float s = 0.f;
    #pragma unroll
    for (int c = 0; c < 16; ++c) { e[c] = __expf(gnb[c] - mx); s += e[c]; }
    const float inv = 1.0f / s;
    const float* Pb = P + (long)b * 256 * 256 + i;
    #pragma unroll
    for (int g = 0; g < 16; ++g) {
        float acc = 0.f;
        #pragma unroll
        for (int c = 0; c < 16; ++c) acc += e[c] * Pb[(long)(g * 16 + c) * 256];
        W2[((long)b * 16 + g) * 256 + i] = acc * inv;
    }
}

// ---------------------------------------------------------------------------
// WP[b][g][n] = W2_b[g] . X_b[:,n]   (pre-sigmoid gating weights)
// ---------------------------------------------------------------------------
__global__ __launch_bounds__(256) void wpre_kernel(
    const float* __restrict__ W2, const float* __restrict__ X, float* __restrict__ WP)
{
    __shared__ float w2s[16][260];
    const int b = blockIdx.y;
    const int n = blockIdx.x * 256 + threadIdx.x;
    for (int f = threadIdx.x; f < 16 * 64; f += 256) {
        const int g = f >> 6, c4 = f & 63;
        *(float4*)&w2s[g][c4 * 4] = *(const float4*)(W2 + ((long)b * 16 + g) * 256 + c4 * 4);
    }
    __syncthreads();
    float acc[16] = {};
    const float* xb = X + (long)b * 256 * 4096 + n;
    for (int k = 0; k < 256; ++k) {
        const float xv = xb[(long)k * 4096];
        #pragma unroll
        for (int g = 0; g < 16; ++g) acc[g] += w2s[g][k] * xv;
    }
    #pragma unroll
    for (int g = 0; g < 16; ++g) WP[((long)b * 16 + g) * 4096 + n] = acc[g];
}

// ---------------------------------------------------------------------------
extern "C" void kernel_launch(void* const* d_in, const int* in_sizes, int n_in,
                              void* d_out, int out_size, void* d_ws, size_t ws_size,
                              hipStream_t stream)
{
    const float* x     = (const float*)d_in[0];
    const float* gnb   = (const float*)d_in[4];
    const float* wqkv  = (const float*)d_in[5];
    const float* wproj = (const float*)d_in[6];
    const float* temp  = (const float*)d_in[7];
    float* out = (float*)d_out;

    // workspace layout (floats): G(1M) T(3M) M(1M) P(1M) W2(64K) WP(1M)  ~29.6 MB
    float* ws = (float*)d_ws;
    float* G  = ws;
    float* T  = G  + 16L * 65536;
    float* Mm = T  + 16L * 196608;
    float* P  = Mm + 16L * 65536;
    float* W2 = P  + 16L * 65536;
    float* WP = W2 + 16L * 4096;

    // 1. Gram: G_b = X_b X_b^T          (256x256, K=4096 per batch)
    gemm64<true, false><<<dim3(4, 4, 16), 256, 0, stream>>>(
        x, x, G, 256, 256, 4096, 1048576L, 1048576L, 65536L, nullptr, nullptr);
    // 2. T = w_qkv @ G_b                (768x256, K=256)
    gemm64<false, false><<<dim3(4, 12, 16), 256, 0, stream>>>(
        wqkv, G, T, 768, 256, 256, 0L, 65536L, 196608L, nullptr, nullptr);
    // 3. attention in Gram space -> M_b (256x256)
    attn_kernel<<<128, 256, 0, stream>>>(T, wqkv, temp, Mm);
    // 4. P_b = w_proj @ M_b             (256x256, K=256)
    gemm64<false, false><<<dim3(4, 4, 16), 256, 0, stream>>>(
        wproj, Mm, P, 256, 256, 256, 0L, 65536L, 65536L, nullptr, nullptr);
    // 5. W2 rows = softmax(gn_b)-weighted group sums of P rows
    w2_kernel<<<16, 256, 0, stream>>>(P, gnb, W2);
    // 6. gating weights WP = W2_b @ X_b (16x4096, K=256)
    wpre_kernel<<<dim3(16, 16), 256, 0, stream>>>(W2, x, WP);
    // 7. Out = P_b @ X_b with fused epilogue y = x*sigmoid(WP) + out
    gemm64<false, true><<<dim3(64, 4, 16), 256, 0, stream>>>(
        P, x, out, 256, 4096, 256, 65536L, 1048576L, 1048576L, x, WP);
}

// Round 2
// 263.871 us; speedup vs baseline: 1.7104x; 1.7104x over previous
//
#include <hip/hip_runtime.h>
#include <math.h>

// Problem constants: B=16, C=256, H=W=64, N=4096, GROUPS=16 (cg=16), HEADS=8 (ch=32)

__device__ __forceinline__ float sigmoidf_(float v) { return 1.0f / (1.0f + __expf(-v)); }

typedef _Float16 half8 __attribute__((ext_vector_type(8)));
typedef _Float16 half4 __attribute__((ext_vector_type(4)));
typedef _Float16 half2v __attribute__((ext_vector_type(2)));
typedef float f32x4 __attribute__((ext_vector_type(4)));

#define GLOAD_LDS16(gp, lp)                                                     \
    __builtin_amdgcn_global_load_lds(                                           \
        (const __attribute__((address_space(1))) void*)(gp),                    \
        (__attribute__((address_space(3))) void*)(lp), 16, 0, 0)

// ---------------------------------------------------------------------------
// Prep: X (fp32 [b][256][4096]) -> Xh (f16 row-major) + Xt (f16 [b][4096][256])
// 64x64 tiles, fp32 LDS staging for the transpose.
// ---------------------------------------------------------------------------
__global__ __launch_bounds__(256) void prep_kernel(
    const float* __restrict__ X, _Float16* __restrict__ Xh, _Float16* __restrict__ Xt)
{
    __shared__ float tile[64][65];
    const int b = blockIdx.z, c0 = blockIdx.y * 64, n0 = blockIdx.x * 64;
    const int t = threadIdx.x;
    const int tc = t & 31;   // col-pair: cols 2tc, 2tc+1
    const int tr = t >> 5;   // row base (8 rows, stride 8)
    const float* Xb = X + ((long)b * 256 + c0) * 4096 + n0;

    #pragma unroll
    for (int i = 0; i < 8; ++i) {
        const int r = tr + i * 8;
        const float2 v = *(const float2*)(Xb + (long)r * 4096 + 2 * tc);
        tile[r][2 * tc] = v.x;
        tile[r][2 * tc + 1] = v.y;
        half2v hv = { (_Float16)v.x, (_Float16)v.y };
        *(half2v*)(Xh + ((long)b * 256 + c0 + r) * 4096 + n0 + 2 * tc) = hv;
    }
    __syncthreads();
    #pragma unroll
    for (int i = 0; i < 8; ++i) {
        const int n = tr + i * 8;
        half2v tv = { (_Float16)tile[2 * tc][n], (_Float16)tile[2 * tc + 1][n] };
        *(half2v*)(Xt + ((long)b * 4096 + n0 + n) * 256 + c0 + 2 * tc) = tv;
    }
}

// ---------------------------------------------------------------------------
// fp32 -> f16 convert (for P)
// ---------------------------------------------------------------------------
__global__ __launch_bounds__(256) void cvt_half(const float* __restrict__ in,
                                                _Float16* __restrict__ o)
{
    const long i = ((long)blockIdx.x * 256 + threadIdx.x) * 4;
    const float4 v = *(const float4*)(in + i);
    half4 h = { (_Float16)v.x, (_Float16)v.y, (_Float16)v.z, (_Float16)v.w };
    *(half4*)(o + i) = h;
}

// ---------------------------------------------------------------------------
// Gram: G_b = Xh_b . Xh_b^T  (256x256, K=4096). m97 structure: 128x128 tile,
// BK=32, global_load_lds(16B), 4 waves x (4x4) 16x16x32 f16 MFMA frags.
// ---------------------------------------------------------------------------
__global__ __launch_bounds__(256) void gram_mfma(const _Float16* __restrict__ Xh,
                                                 float* __restrict__ G)
{
    __shared__ _Float16 Al[128 * 32];
    __shared__ _Float16 Bl[128 * 32];
    const int b = blockIdx.z;
    const int m0 = blockIdx.y * 128, n0 = blockIdx.x * 128;
    const _Float16* Xb = Xh + (long)b * 256 * 4096;
    const int t = threadIdx.x, lane = t & 63, wv = t >> 6;
    const int wm = (wv >> 1) * 64, wn = (wv & 1) * 64;
    f32x4 acc[4][4] = {};

    for (int k0 = 0; k0 < 4096; k0 += 32) {
        __syncthreads();
        #pragma unroll
        for (int r = 0; r < 2; ++r) {
            const int e = (r * 256 + t) * 8;       // f16 elem index in tile
            const int row = e >> 5, col = e & 31;  // 32 f16 per tile row
            GLOAD_LDS16(Xb + (long)(m0 + row) * 4096 + k0 + col, &Al[e]);
            GLOAD_LDS16(Xb + (long)(n0 + row) * 4096 + k0 + col, &Bl[e]);
        }
        __syncthreads();
        half8 af[4], bf[4];
        #pragma unroll
        for (int f = 0; f < 4; ++f) {
            af[f] = *(const half8*)&Al[(wm + f * 16 + (lane & 15)) * 32 + (lane >> 4) * 8];
            bf[f] = *(const half8*)&Bl[(wn + f * 16 + (lane & 15)) * 32 + (lane >> 4) * 8];
        }
        #pragma unroll
        for (int i = 0; i < 4; ++i)
            #pragma unroll
            for (int j = 0; j < 4; ++j)
                acc[i][j] = __builtin_amdgcn_mfma_f32_16x16x32_f16(af[i], bf[j], acc[i][j], 0, 0, 0);
    }
    #pragma unroll
    for (int i = 0; i < 4; ++i)
        #pragma unroll
        for (int j = 0; j < 4; ++j) {
            const int row = m0 + wm + i * 16 + (lane >> 4) * 4;
            const int col = n0 + wn + j * 16 + (lane & 15);
            float* gp = G + (long)b * 65536 + (long)row * 256 + col;
            #pragma unroll
            for (int r = 0; r < 4; ++r) gp[(long)r * 256] = acc[i][j][r];
        }
}

// ---------------------------------------------------------------------------
// Out: out_b = Ph_b(256x256) @ X_b  via BT form with Xt (K-contiguous rows),
// fused epilogue y = Xh*sigmoid(WP) + acc.
// ---------------------------------------------------------------------------
__global__ __launch_bounds__(256) void out_mfma(
    const _Float16* __restrict__ Ph, const _Float16* __restrict__ Xt,
    const _Float16* __restrict__ Xh, const float* __restrict__ WP,
    float* __restrict__ out)
{
    __shared__ _Float16 Al[128 * 32];
    __shared__ _Float16 Bl[128 * 32];
    const int b = blockIdx.z;
    const int m0 = blockIdx.y * 128;   // c
    const int n0 = blockIdx.x * 128;   // n
    const _Float16* Ab = Ph + (long)b * 65536;
    const _Float16* Bb = Xt + (long)b * 1048576;
    const int t = threadIdx.x, lane = t & 63, wv = t >> 6;
    const int wm = (wv >> 1) * 64, wn = (wv & 1) * 64;
    f32x4 acc[4][4] = {};

    for (int k0 = 0; k0 < 256; k0 += 32) {
        __syncthreads();
        #pragma unroll
        for (int r = 0; r < 2; ++r) {
            const int e = (r * 256 + t) * 8;
            const int row = e >> 5, col = e & 31;
            GLOAD_LDS16(Ab + (long)(m0 + row) * 256 + k0 + col, &Al[e]);
            GLOAD_LDS16(Bb + (long)(n0 + row) * 256 + k0 + col, &Bl[e]);
        }
        __syncthreads();
        half8 af[4], bf[4];
        #pragma unroll
        for (int f = 0; f < 4; ++f) {
            af[f] = *(const half8*)&Al[(wm + f * 16 + (lane & 15)) * 32 + (lane >> 4) * 8];
            bf[f] = *(const half8*)&Bl[(wn + f * 16 + (lane & 15)) * 32 + (lane >> 4) * 8];
        }
        #pragma unroll
        for (int i = 0; i < 4; ++i)
            #pragma unroll
            for (int j = 0; j < 4; ++j)
                acc[i][j] = __builtin_amdgcn_mfma_f32_16x16x32_f16(af[i], bf[j], acc[i][j], 0, 0, 0);
    }
    const float* WPb = WP + (long)b * 16 * 4096;
    const _Float16* Xhb = Xh + (long)b * 1048576;
    float* ob = out + (long)b * 1048576;
    #pragma unroll
    for (int i = 0; i < 4; ++i)
        #pragma unroll
        for (int j = 0; j < 4; ++j) {
            const int row0 = m0 + wm + i * 16 + (lane >> 4) * 4;
            const int col = n0 + wn + j * 16 + (lane & 15);
            #pragma unroll
            for (int r = 0; r < 4; ++r) {
                const int c = row0 + r;
                const float xv = (float)Xhb[(long)c * 4096 + col];
                const float wpv = WPb[(long)(c >> 4) * 4096 + col];
                ob[(long)c * 4096 + col] = xv * sigmoidf_(wpv) + acc[i][j][r];
            }
        }
}

// ---------------------------------------------------------------------------
// Generic 64x64-tile fp32 GEMM (round-1), used for small GEMMs + fallback.
// ---------------------------------------------------------------------------
template <bool BT, bool EPI>
__global__ __launch_bounds__(256) void gemm64(
    const float* __restrict__ A, const float* __restrict__ B, float* __restrict__ C,
    int M, int N, int K, long sA, long sB, long sC,
    const float* __restrict__ X, const float* __restrict__ WP)
{
    __shared__ float As[32][68];
    __shared__ float Bs[32][68];
    const int b = blockIdx.z;
    const float* Ab = A + (long)b * sA;
    const float* Bb = B + (long)b * sB;
    float* Cb = C + (long)b * sC;
    const int t = threadIdx.x;
    const int tx = t & 15, ty = t >> 4;
    const int m0 = blockIdx.y * 64, n0 = blockIdx.x * 64;

    float acc[4][4] = {};

    for (int k0 = 0; k0 < K; k0 += 32) {
        __syncthreads();
        #pragma unroll
        for (int f0 = 0; f0 < 512; f0 += 256) {
            const int f = f0 + t;
            const int row = f >> 3, c4 = f & 7;
            const float4 v = *(const float4*)(Ab + (long)(m0 + row) * K + k0 + c4 * 4);
            As[c4 * 4 + 0][row] = v.x;
            As[c4 * 4 + 1][row] = v.y;
            As[c4 * 4 + 2][row] = v.z;
            As[c4 * 4 + 3][row] = v.w;
        }
        if (BT) {
            #pragma unroll
            for (int f0 = 0; f0 < 512; f0 += 256) {
                const int f = f0 + t;
                const int row = f >> 3, c4 = f & 7;
                const float4 v = *(const float4*)(Bb + (long)(n0 + row) * K + k0 + c4 * 4);
                Bs[c4 * 4 + 0][row] = v.x;
                Bs[c4 * 4 + 1][row] = v.y;
                Bs[c4 * 4 + 2][row] = v.z;
                Bs[c4 * 4 + 3][row] = v.w;
            }
        } else {
            #pragma unroll
            for (int f0 = 0; f0 < 512; f0 += 256) {
                const int f = f0 + t;
                const int kk = f >> 4, c4 = f & 15;
                *(float4*)&Bs[kk][c4 * 4] =
                    *(const float4*)(Bb + (long)(k0 + kk) * N + n0 + c4 * 4);
            }
        }
        __syncthreads();
        #pragma unroll
        for (int kk = 0; kk < 32; ++kk) {
            const float4 av = *(const float4*)&As[kk][ty * 4];
            const float4 bv = *(const float4*)&Bs[kk][tx * 4];
            const float a0 = av.x, a1 = av.y, a2 = av.z, a3 = av.w;
            const float b0 = bv.x, b1 = bv.y, b2 = bv.z, b3 = bv.w;
            acc[0][0] += a0 * b0; acc[0][1] += a0 * b1; acc[0][2] += a0 * b2; acc[0][3] += a0 * b3;
            acc[1][0] += a1 * b0; acc[1][1] += a1 * b1; acc[1][2] += a1 * b2; acc[1][3] += a1 * b3;
            acc[2][0] += a2 * b0; acc[2][1] += a2 * b1; acc[2][2] += a2 * b2; acc[2][3] += a2 * b3;
            acc[3][0] += a3 * b0; acc[3][1] += a3 * b1; acc[3][2] += a3 * b2; acc[3][3] += a3 * b3;
        }
    }

    if (EPI) {
        #pragma unroll
        for (int i = 0; i < 4; ++i) {
            const int c = m0 + ty * 4 + i;
            const long nidx = n0 + tx * 4;
            const float4 xv = *(const float4*)(X + ((long)b * 256 + c) * 4096 + nidx);
            const float4 wv = *(const float4*)(WP + ((long)b * 16 + (c >> 4)) * 4096 + nidx);
            float4 o;
            o.x = xv.x * sigmoidf_(wv.x) + acc[i][0];
            o.y = xv.y * sigmoidf_(wv.y) + acc[i][1];
            o.z = xv.z * sigmoidf_(wv.z) + acc[i][2];
            o.w = xv.w * sigmoidf_(wv.w) + acc[i][3];
            *(float4*)(Cb + (long)c * N + nidx) = o;
        }
    } else {
        #pragma unroll
        for (int i = 0; i < 4; ++i) {
            const float4 o = make_float4(acc[i][0], acc[i][1], acc[i][2], acc[i][3]);
            *(float4*)(Cb + (long)(m0 + ty * 4 + i) * N + n0 + tx * 4) = o;
        }
    }
}

// ---------------------------------------------------------------------------
// Per-(b,h) attention in Gram space (unchanged from round 1).
// ---------------------------------------------------------------------------
__global__ __launch_bounds__(256) void attn_kernel(
    const float* __restrict__ T, const float* __restrict__ wqkv,
    const float* __restrict__ temp, float* __restrict__ Mout)
{
    const int bh = blockIdx.x;
    const int b = bh >> 3, h = bh & 7;
    const int t = threadIdx.x;
    __shared__ float Tq[32][260];
    __shared__ float qk[32][33];
    __shared__ float qn[32], kn[32];
    const float* Tb = T + (long)b * 768 * 256;

    for (int f = t; f < 32 * 64; f += 256) {
        const int r = f >> 6, c4 = f & 63;
        *(float4*)&Tq[r][c4 * 4] = *(const float4*)(Tb + (long)(h * 32 + r) * 256 + c4 * 4);
    }
    __syncthreads();

    if (t < 32) {
        float s = 0.f;
        const float* wq = wqkv + (long)(h * 32 + t) * 256;
        #pragma unroll 4
        for (int k = 0; k < 256; k += 4) {
            const float4 a = *(const float4*)&Tq[t][k];
            const float4 w = *(const float4*)(wq + k);
            s += a.x * w.x + a.y * w.y + a.z * w.z + a.w * w.w;
        }
        qn[t] = fmaxf(sqrtf(s), 1e-12f);
    } else if (t < 64) {
        const int d = t - 32;
        float s = 0.f;
        const float* tk = Tb + (long)(256 + h * 32 + d) * 256;
        const float* wk = wqkv + (long)(256 + h * 32 + d) * 256;
        #pragma unroll 4
        for (int k = 0; k < 256; k += 4) {
            const float4 a = *(const float4*)(tk + k);
            const float4 w = *(const float4*)(wk + k);
            s += a.x * w.x + a.y * w.y + a.z * w.z + a.w * w.w;
        }
        kn[d] = fmaxf(sqrtf(s), 1e-12f);
    }

    {
        const int c = t >> 3, d0 = (t & 7) * 4;
        float s0 = 0, s1 = 0, s2 = 0, s3 = 0;
        const float* wk0 = wqkv + (long)(256 + h * 32 + d0) * 256;
        #pragma unroll 4
        for (int k = 0; k < 256; k += 4) {
            const float4 a = *(const float4*)&Tq[c][k];
            const float4 w0 = *(const float4*)(wk0 + k);
            const float4 w1 = *(const float4*)(wk0 + 256 + k);
            const float4 w2 = *(const float4*)(wk0 + 512 + k);
            const float4 w3 = *(const float4*)(wk0 + 768 + k);
            s0 += a.x * w0.x + a.y * w0.y + a.z * w0.z + a.w * w0.w;
            s1 += a.x * w1.x + a.y * w1.y + a.z * w1.z + a.w * w1.w;
            s2 += a.x * w2.x + a.y * w2.y + a.z * w2.z + a.w * w2.w;
            s3 += a.x * w3.x + a.y * w3.y + a.z * w3.z + a.w * w3.w;
        }
        qk[c][d0 + 0] = s0;
        qk[c][d0 + 1] = s1;
        qk[c][d0 + 2] = s2;
        qk[c][d0 + 3] = s3;
    }
    __syncthreads();

    if (t < 32) {
        const float tscale = temp[h];
        const float qin = tscale / qn[t];
        float lg[32];
        float mx = -1e30f;
        #pragma unroll
        for (int d = 0; d < 32; ++d) {
            const float l = qk[t][d] * qin / kn[d];
            lg[d] = l;
            mx = fmaxf(mx, l);
        }
        float s = 0.f;
        #pragma unroll
        for (int d = 0; d < 32; ++d) { lg[d] = __expf(lg[d] - mx); s += lg[d]; }
        const float inv = 1.0f / s;
        #pragma unroll
        for (int d = 0; d < 32; ++d) qk[t][d] = lg[d] * inv;
    }
    __syncthreads();

    float accm[32];
    #pragma unroll
    for (int c = 0; c < 32; ++c) accm[c] = 0.f;
    const float* wvp = wqkv + (long)(512 + h * 32) * 256 + t;
    #pragma unroll 4
    for (int d = 0; d < 32; ++d) {
        const float wvv = wvp[(long)d * 256];
        #pragma unroll
        for (int c = 0; c < 32; ++c) accm[c] += qk[c][d] * wvv;
    }
    float* mo = Mout + (long)b * 256 * 256 + (long)(h * 32) * 256 + t;
    #pragma unroll
    for (int c = 0; c < 32; ++c) mo[(long)c * 256] = accm[c];
}

__global__ __launch_bounds__(256) void w2_kernel(
    const float* __restrict__ P, const float* __restrict__ gnb, float* __restrict__ W2)
{
    const int b = blockIdx.x, i = threadIdx.x;
    float e[16];
    float mx = -1e30f;
    #pragma unroll
    for (int c = 0; c < 16; ++c) mx = fmaxf(mx, gnb[c]);
    float s = 0.f;
    #pragma unroll
    for (int c = 0; c < 16; ++c) { e[c] = __expf(gnb[c] - mx); s += e[c]; }
    const float inv = 1.0f / s;
    const float* Pb = P + (long)b * 256 * 256 + i;
    #pragma unroll
    for (int g = 0; g < 16; ++g) {
        float acc = 0.f;
        #pragma unroll
        for (int c = 0; c < 16; ++c) acc += e[c] * Pb[(long)(g * 16 + c) * 256];
        W2[((long)b * 16 + g) * 256 + i] = acc * inv;
    }
}

__global__ __launch_bounds__(256) void wpre_kernel(
    const float* __restrict__ W2, const float* __restrict__ X, float* __restrict__ WP)
{
    __shared__ float w2s[16][260];
    const int b = blockIdx.y;
    const int n = blockIdx.x * 256 + threadIdx.x;
    for (int f = threadIdx.x; f < 16 * 64; f += 256) {
        const int g = f >> 6, c4 = f & 63;
        *(float4*)&w2s[g][c4 * 4] = *(const float4*)(W2 + ((long)b * 16 + g) * 256 + c4 * 4);
    }
    __syncthreads();
    float acc[16] = {};
    const float* xb = X + (long)b * 256 * 4096 + n;
    for (int k = 0; k < 256; ++k) {
        const float xv = xb[(long)k * 4096];
        #pragma unroll
        for (int g = 0; g < 16; ++g) acc[g] += w2s[g][k] * xv;
    }
    #pragma unroll
    for (int g = 0; g < 16; ++g) WP[((long)b * 16 + g) * 4096 + n] = acc[g];
}

// ---------------------------------------------------------------------------
extern "C" void kernel_launch(void* const* d_in, const int* in_sizes, int n_in,
                              void* d_out, int out_size, void* d_ws, size_t ws_size,
                              hipStream_t stream)
{
    const float* x     = (const float*)d_in[0];
    const float* gnb   = (const float*)d_in[4];
    const float* wqkv  = (const float*)d_in[5];
    const float* wproj = (const float*)d_in[6];
    const float* temp  = (const float*)d_in[7];
    float* out = (float*)d_out;

    if (ws_size >= 82051072ULL) {
        // Fast path (f16 MFMA for the two big GEMMs). Workspace overlay:
        //  [Xh 32M][Xt 32M][G|Mm 4M][pool 12M: T -> {P, Ph, W2, WP}]
        char* w = (char*)d_ws;
        _Float16* Xh = (_Float16*)w;
        _Float16* Xt = (_Float16*)(w + 33554432);
        float*    G  = (float*)(w + 67108864);
        float*    Mm = G;                       // overlay: G dead before attn writes Mm
        char*     pool = w + 71303168;
        float*    T  = (float*)pool;            // dead after attn
        float*    P  = (float*)pool;            // written after attn
        _Float16* Ph = (_Float16*)(pool + 4194304);
        float*    W2 = (float*)(pool + 4194304 + 2097152);
        float*    WP = (float*)(pool + 4194304 + 2097152 + 262144);

        // 1. X -> Xh (f16), Xt (f16 transposed)
        prep_kernel<<<dim3(64, 4, 16), 256, 0, stream>>>(x, Xh, Xt);
        // 2. Gram: G_b = Xh_b Xh_b^T (MFMA)
        gram_mfma<<<dim3(2, 2, 16), 256, 0, stream>>>(Xh, G);
        // 3. T = w_qkv @ G_b
        gemm64<false, false><<<dim3(4, 12, 16), 256, 0, stream>>>(
            wqkv, G, T, 768, 256, 256, 0L, 65536L, 196608L, nullptr, nullptr);
        // 4. attention in Gram space -> Mm
        attn_kernel<<<128, 256, 0, stream>>>(T, wqkv, temp, Mm);
        // 5. P_b = w_proj @ Mm_b
        gemm64<false, false><<<dim3(4, 4, 16), 256, 0, stream>>>(
            wproj, Mm, P, 256, 256, 256, 0L, 65536L, 65536L, nullptr, nullptr);
        // 6. P -> f16
        cvt_half<<<1024, 256, 0, stream>>>(P, Ph);
        // 7. W2 = softmax(gn_b)-weighted group sums of P rows
        w2_kernel<<<16, 256, 0, stream>>>(P, gnb, W2);
        // 8. WP = W2_b @ X_b
        wpre_kernel<<<dim3(16, 16), 256, 0, stream>>>(W2, x, WP);
        // 9. out = Ph_b @ X_b (via Xt, MFMA) + fused gating epilogue
        out_mfma<<<dim3(32, 2, 16), 256, 0, stream>>>(Ph, Xt, Xh, WP, out);
    } else {
        // Fallback: round-1 fp32 path (~30 MB workspace)
        float* ws = (float*)d_ws;
        float* G  = ws;
        float* T  = G  + 16L * 65536;
        float* Mm = T  + 16L * 196608;
        float* P  = Mm + 16L * 65536;
        float* W2 = P  + 16L * 65536;
        float* WP = W2 + 16L * 4096;

        gemm64<true, false><<<dim3(4, 4, 16), 256, 0, stream>>>(
            x, x, G, 256, 256, 4096, 1048576L, 1048576L, 65536L, nullptr, nullptr);
        gemm64<false, false><<<dim3(4, 12, 16), 256, 0, stream>>>(
            wqkv, G, T, 768, 256, 256, 0L, 65536L, 196608L, nullptr, nullptr);
        attn_kernel<<<128, 256, 0, stream>>>(T, wqkv, temp, Mm);
        gemm64<false, false><<<dim3(4, 4, 16), 256, 0, stream>>>(
            wproj, Mm, P, 256, 256, 256, 0L, 65536L, 65536L, nullptr, nullptr);
        w2_kernel<<<16, 256, 0, stream>>>(P, gnb, W2);
        wpre_kernel<<<dim3(16, 16), 256, 0, stream>>>(W2, x, WP);
        gemm64<false, true><<<dim3(64, 4, 16), 256, 0, stream>>>(
            P, x, out, 256, 4096, 256, 65536L, 1048576L, 1048576L, x, WP);
    }
}

// Round 4
// 215.161 us; speedup vs baseline: 2.0976x; 1.2264x over previous
//
#include <hip/hip_runtime.h>
#include <math.h>

// Problem constants: B=16, C=256, H=W=64, N=4096, GROUPS=16 (cg=16), HEADS=8 (ch=32)

__device__ __forceinline__ float sigmoidf_(float v) { return 1.0f / (1.0f + __expf(-v)); }

typedef _Float16 half8 __attribute__((ext_vector_type(8)));
typedef _Float16 half4 __attribute__((ext_vector_type(4)));
typedef _Float16 half2v __attribute__((ext_vector_type(2)));
typedef float f32x4 __attribute__((ext_vector_type(4)));

#define GLOAD_LDS16(gp, lp)                                                     \
    __builtin_amdgcn_global_load_lds(                                           \
        (const __attribute__((address_space(1))) void*)(gp),                    \
        (__attribute__((address_space(3))) void*)(lp), 16, 0, 0)

// ---------------------------------------------------------------------------
// Prep: X (fp32) -> Xh (f16 row-major). Pure elementwise, 8 elems/thread.
// ---------------------------------------------------------------------------
__global__ __launch_bounds__(256) void prep_kernel(
    const float* __restrict__ X, _Float16* __restrict__ Xh)
{
    const long i = ((long)blockIdx.x * 256 + threadIdx.x) * 8;
    const float4 v0 = *(const float4*)(X + i);
    const float4 v1 = *(const float4*)(X + i + 4);
    half8 h = { (_Float16)v0.x, (_Float16)v0.y, (_Float16)v0.z, (_Float16)v0.w,
                (_Float16)v1.x, (_Float16)v1.y, (_Float16)v1.z, (_Float16)v1.w };
    *(half8*)(Xh + i) = h;
}

// ---------------------------------------------------------------------------
// Transpose: Xh [b][256][4096] -> Xt [b][4096][256]  (f16, 64x64 LDS tiles)
// Runs AFTER gram reduce (Xt region doubles as split-K partial buffer).
// ---------------------------------------------------------------------------
__global__ __launch_bounds__(256) void transpose_xt(
    const _Float16* __restrict__ Xh, _Float16* __restrict__ Xt)
{
    __shared__ _Float16 tl[64][72];
    const int b = blockIdx.z, c0 = blockIdx.y * 64, n0 = blockIdx.x * 64;
    const int t = threadIdx.x;
    const int r8 = t >> 3, cb = (t & 7) * 8;
    #pragma unroll
    for (int i = 0; i < 2; ++i) {
        const int cc = r8 + 32 * i;
        *(half8*)&tl[cc][cb] =
            *(const half8*)(Xh + ((long)b * 256 + c0 + cc) * 4096 + n0 + cb);
    }
    __syncthreads();
    #pragma unroll
    for (int i = 0; i < 2; ++i) {
        const int nn = r8 + 32 * i;
        half8 v;
        #pragma unroll
        for (int k = 0; k < 8; ++k) v[k] = tl[cb + k][nn];
        *(half8*)(Xt + ((long)b * 4096 + n0 + nn) * 256 + c0 + cb) = v;
    }
}

// ---------------------------------------------------------------------------
// fp32 -> f16 convert (for P)
// ---------------------------------------------------------------------------
__global__ __launch_bounds__(256) void cvt_half(const float* __restrict__ in,
                                                _Float16* __restrict__ o)
{
    const long i = ((long)blockIdx.x * 256 + threadIdx.x) * 4;
    const float4 v = *(const float4*)(in + i);
    half4 h = { (_Float16)v.x, (_Float16)v.y, (_Float16)v.z, (_Float16)v.w };
    *(half4*)(o + i) = h;
}

// ---------------------------------------------------------------------------
// Gram split-K: pG[s][b] = Xh_b[:, s*512:(s+1)*512] . (same)^T
// 128x128 tile, BK=32, global_load_lds(16B), 4 waves x (4x4) 16x16x32 f16.
// blockIdx.z = b*8 + s -> 512 workgroups (2 blocks/CU).
// Slab stride: 16 batches x 65536 floats = 1048576 floats per split (4 MB).
// (Round-3 bug: stride 16777216 wrote ~470 MB OOB, corrupting inputs.)
// ---------------------------------------------------------------------------
__global__ __launch_bounds__(256) void gram_split(const _Float16* __restrict__ Xh,
                                                  float* __restrict__ pG)
{
    __shared__ _Float16 Al[128 * 32];
    __shared__ _Float16 Bl[128 * 32];
    const int z = blockIdx.z, b = z >> 3, s = z & 7;
    const int m0 = blockIdx.y * 128, n0 = blockIdx.x * 128;
    const _Float16* Xb = Xh + (long)b * 256 * 4096;
    const int t = threadIdx.x, lane = t & 63, wv = t >> 6;
    const int wm = (wv >> 1) * 64, wn = (wv & 1) * 64;
    f32x4 acc[4][4] = {};

    const int kbeg = s * 512, kend = kbeg + 512;
    for (int k0 = kbeg; k0 < kend; k0 += 32) {
        __syncthreads();
        #pragma unroll
        for (int r = 0; r < 2; ++r) {
            const int e = (r * 256 + t) * 8;
            const int row = e >> 5, col = e & 31;
            GLOAD_LDS16(Xb + (long)(m0 + row) * 4096 + k0 + col, &Al[e]);
            GLOAD_LDS16(Xb + (long)(n0 + row) * 4096 + k0 + col, &Bl[e]);
        }
        __syncthreads();
        half8 af[4], bf[4];
        #pragma unroll
        for (int f = 0; f < 4; ++f) {
            af[f] = *(const half8*)&Al[(wm + f * 16 + (lane & 15)) * 32 + (lane >> 4) * 8];
            bf[f] = *(const half8*)&Bl[(wn + f * 16 + (lane & 15)) * 32 + (lane >> 4) * 8];
        }
        #pragma unroll
        for (int i = 0; i < 4; ++i)
            #pragma unroll
            for (int j = 0; j < 4; ++j)
                acc[i][j] = __builtin_amdgcn_mfma_f32_16x16x32_f16(af[i], bf[j], acc[i][j], 0, 0, 0);
    }
    float* pGb = pG + (long)s * 1048576 + (long)b * 65536;
    #pragma unroll
    for (int i = 0; i < 4; ++i)
        #pragma unroll
        for (int j = 0; j < 4; ++j) {
            const int row = m0 + wm + i * 16 + (lane >> 4) * 4;
            const int col = n0 + wn + j * 16 + (lane & 15);
            float* gp = pGb + (long)row * 256 + col;
            #pragma unroll
            for (int r = 0; r < 4; ++r) gp[(long)r * 256] = acc[i][j][r];
        }
}

// ---------------------------------------------------------------------------
// G = sum_s pG[s]  (fixed order -> deterministic)
// ---------------------------------------------------------------------------
__global__ __launch_bounds__(256) void reduce_g(const float* __restrict__ pG,
                                                float* __restrict__ G)
{
    const long i = ((long)blockIdx.x * 256 + threadIdx.x) * 4;
    f32x4 s = {};
    #pragma unroll
    for (int k = 0; k < 8; ++k) {
        const float4 v = *(const float4*)(pG + (long)k * 1048576 + i);
        s[0] += v.x; s[1] += v.y; s[2] += v.z; s[3] += v.w;
    }
    *(f32x4*)(G + i) = s;
}

// ---------------------------------------------------------------------------
// Out: out_b = Ph_b(256x256) @ X_b via Xt rows (K-contiguous), fused epilogue.
// ---------------------------------------------------------------------------
__global__ __launch_bounds__(256) void out_mfma(
    const _Float16* __restrict__ Ph, const _Float16* __restrict__ Xt,
    const _Float16* __restrict__ Xh, const float* __restrict__ WP,
    float* __restrict__ out)
{
    __shared__ _Float16 Al[128 * 32];
    __shared__ _Float16 Bl[128 * 32];
    const int b = blockIdx.z;
    const int m0 = blockIdx.y * 128;   // c
    const int n0 = blockIdx.x * 128;   // n
    const _Float16* Ab = Ph + (long)b * 65536;
    const _Float16* Bb = Xt + (long)b * 1048576;
    const int t = threadIdx.x, lane = t & 63, wv = t >> 6;
    const int wm = (wv >> 1) * 64, wn = (wv & 1) * 64;
    f32x4 acc[4][4] = {};

    for (int k0 = 0; k0 < 256; k0 += 32) {
        __syncthreads();
        #pragma unroll
        for (int r = 0; r < 2; ++r) {
            const int e = (r * 256 + t) * 8;
            const int row = e >> 5, col = e & 31;
            GLOAD_LDS16(Ab + (long)(m0 + row) * 256 + k0 + col, &Al[e]);
            GLOAD_LDS16(Bb + (long)(n0 + row) * 256 + k0 + col, &Bl[e]);
        }
        __syncthreads();
        half8 af[4], bf[4];
        #pragma unroll
        for (int f = 0; f < 4; ++f) {
            af[f] = *(const half8*)&Al[(wm + f * 16 + (lane & 15)) * 32 + (lane >> 4) * 8];
            bf[f] = *(const half8*)&Bl[(wn + f * 16 + (lane & 15)) * 32 + (lane >> 4) * 8];
        }
        #pragma unroll
        for (int i = 0; i < 4; ++i)
            #pragma unroll
            for (int j = 0; j < 4; ++j)
                acc[i][j] = __builtin_amdgcn_mfma_f32_16x16x32_f16(af[i], bf[j], acc[i][j], 0, 0, 0);
    }
    const float* WPb = WP + (long)b * 16 * 4096;
    const _Float16* Xhb = Xh + (long)b * 1048576;
    float* ob = out + (long)b * 1048576;
    #pragma unroll
    for (int i = 0; i < 4; ++i)
        #pragma unroll
        for (int j = 0; j < 4; ++j) {
            const int row0 = m0 + wm + i * 16 + (lane >> 4) * 4;
            const int col = n0 + wn + j * 16 + (lane & 15);
            #pragma unroll
            for (int r = 0; r < 4; ++r) {
                const int c = row0 + r;
                const float xv = (float)Xhb[(long)c * 4096 + col];
                const float wpv = WPb[(long)(c >> 4) * 4096 + col];
                ob[(long)c * 4096 + col] = xv * sigmoidf_(wpv) + acc[i][j][r];
            }
        }
}

// ---------------------------------------------------------------------------
// Generic 64x64-tile fp32 GEMM (small GEMMs + fallback path).
// ---------------------------------------------------------------------------
template <bool BT, bool EPI>
__global__ __launch_bounds__(256) void gemm64(
    const float* __restrict__ A, const float* __restrict__ B, float* __restrict__ C,
    int M, int N, int K, long sA, long sB, long sC,
    const float* __restrict__ X, const float* __restrict__ WP)
{
    __shared__ float As[32][68];
    __shared__ float Bs[32][68];
    const int b = blockIdx.z;
    const float* Ab = A + (long)b * sA;
    const float* Bb = B + (long)b * sB;
    float* Cb = C + (long)b * sC;
    const int t = threadIdx.x;
    const int tx = t & 15, ty = t >> 4;
    const int m0 = blockIdx.y * 64, n0 = blockIdx.x * 64;

    float acc[4][4] = {};

    for (int k0 = 0; k0 < K; k0 += 32) {
        __syncthreads();
        #pragma unroll
        for (int f0 = 0; f0 < 512; f0 += 256) {
            const int f = f0 + t;
            const int row = f >> 3, c4 = f & 7;
            const float4 v = *(const float4*)(Ab + (long)(m0 + row) * K + k0 + c4 * 4);
            As[c4 * 4 + 0][row] = v.x;
            As[c4 * 4 + 1][row] = v.y;
            As[c4 * 4 + 2][row] = v.z;
            As[c4 * 4 + 3][row] = v.w;
        }
        if (BT) {
            #pragma unroll
            for (int f0 = 0; f0 < 512; f0 += 256) {
                const int f = f0 + t;
                const int row = f >> 3, c4 = f & 7;
                const float4 v = *(const float4*)(Bb + (long)(n0 + row) * K + k0 + c4 * 4);
                Bs[c4 * 4 + 0][row] = v.x;
                Bs[c4 * 4 + 1][row] = v.y;
                Bs[c4 * 4 + 2][row] = v.z;
                Bs[c4 * 4 + 3][row] = v.w;
            }
        } else {
            #pragma unroll
            for (int f0 = 0; f0 < 512; f0 += 256) {
                const int f = f0 + t;
                const int kk = f >> 4, c4 = f & 15;
                *(float4*)&Bs[kk][c4 * 4] =
                    *(const float4*)(Bb + (long)(k0 + kk) * N + n0 + c4 * 4);
            }
        }
        __syncthreads();
        #pragma unroll
        for (int kk = 0; kk < 32; ++kk) {
            const float4 av = *(const float4*)&As[kk][ty * 4];
            const float4 bv = *(const float4*)&Bs[kk][tx * 4];
            const float a0 = av.x, a1 = av.y, a2 = av.z, a3 = av.w;
            const float b0 = bv.x, b1 = bv.y, b2 = bv.z, b3 = bv.w;
            acc[0][0] += a0 * b0; acc[0][1] += a0 * b1; acc[0][2] += a0 * b2; acc[0][3] += a0 * b3;
            acc[1][0] += a1 * b0; acc[1][1] += a1 * b1; acc[1][2] += a1 * b2; acc[1][3] += a1 * b3;
            acc[2][0] += a2 * b0; acc[2][1] += a2 * b1; acc[2][2] += a2 * b2; acc[2][3] += a2 * b3;
            acc[3][0] += a3 * b0; acc[3][1] += a3 * b1; acc[3][2] += a3 * b2; acc[3][3] += a3 * b3;
        }
    }

    if (EPI) {
        #pragma unroll
        for (int i = 0; i < 4; ++i) {
            const int c = m0 + ty * 4 + i;
            const long nidx = n0 + tx * 4;
            const float4 xv = *(const float4*)(X + ((long)b * 256 + c) * 4096 + nidx);
            const float4 wv = *(const float4*)(WP + ((long)b * 16 + (c >> 4)) * 4096 + nidx);
            float4 o;
            o.x = xv.x * sigmoidf_(wv.x) + acc[i][0];
            o.y = xv.y * sigmoidf_(wv.y) + acc[i][1];
            o.z = xv.z * sigmoidf_(wv.z) + acc[i][2];
            o.w = xv.w * sigmoidf_(wv.w) + acc[i][3];
            *(float4*)(Cb + (long)c * N + nidx) = o;
        }
    } else {
        #pragma unroll
        for (int i = 0; i < 4; ++i) {
            const float4 o = make_float4(acc[i][0], acc[i][1], acc[i][2], acc[i][3]);
            *(float4*)(Cb + (long)(m0 + ty * 4 + i) * N + n0 + tx * 4) = o;
        }
    }
}

// ---------------------------------------------------------------------------
// Per-(b,h) attention in Gram space. tStride = floats per batch of T.
// ---------------------------------------------------------------------------
__global__ __launch_bounds__(256) void attn_kernel(
    const float* __restrict__ T, const float* __restrict__ wqkv,
    const float* __restrict__ temp, float* __restrict__ Mout, long tStride)
{
    const int bh = blockIdx.x;
    const int b = bh >> 3, h = bh & 7;
    const int t = threadIdx.x;
    __shared__ float Tq[32][260];
    __shared__ float qk[32][33];
    __shared__ float qn[32], kn[32];
    const float* Tb = T + (long)b * tStride;

    for (int f = t; f < 32 * 64; f += 256) {
        const int r = f >> 6, c4 = f & 63;
        *(float4*)&Tq[r][c4 * 4] = *(const float4*)(Tb + (long)(h * 32 + r) * 256 + c4 * 4);
    }
    __syncthreads();

    if (t < 32) {
        float s = 0.f;
        const float* wq = wqkv + (long)(h * 32 + t) * 256;
        #pragma unroll 4
        for (int k = 0; k < 256; k += 4) {
            const float4 a = *(const float4*)&Tq[t][k];
            const float4 w = *(const float4*)(wq + k);
            s += a.x * w.x + a.y * w.y + a.z * w.z + a.w * w.w;
        }
        qn[t] = fmaxf(sqrtf(s), 1e-12f);
    } else if (t < 64) {
        const int d = t - 32;
        float s = 0.f;
        const float* tk = Tb + (long)(256 + h * 32 + d) * 256;
        const float* wk = wqkv + (long)(256 + h * 32 + d) * 256;
        #pragma unroll 4
        for (int k = 0; k < 256; k += 4) {
            const float4 a = *(const float4*)(tk + k);
            const float4 w = *(const float4*)(wk + k);
            s += a.x * w.x + a.y * w.y + a.z * w.z + a.w * w.w;
        }
        kn[d] = fmaxf(sqrtf(s), 1e-12f);
    }

    {
        const int c = t >> 3, d0 = (t & 7) * 4;
        float s0 = 0, s1 = 0, s2 = 0, s3 = 0;
        const float* wk0 = wqkv + (long)(256 + h * 32 + d0) * 256;
        #pragma unroll 4
        for (int k = 0; k < 256; k += 4) {
            const float4 a = *(const float4*)&Tq[c][k];
            const float4 w0 = *(const float4*)(wk0 + k);
            const float4 w1 = *(const float4*)(wk0 + 256 + k);
            const float4 w2 = *(const float4*)(wk0 + 512 + k);
            const float4 w3 = *(const float4*)(wk0 + 768 + k);
            s0 += a.x * w0.x + a.y * w0.y + a.z * w0.z + a.w * w0.w;
            s1 += a.x * w1.x + a.y * w1.y + a.z * w1.z + a.w * w1.w;
            s2 += a.x * w2.x + a.y * w2.y + a.z * w2.z + a.w * w2.w;
            s3 += a.x * w3.x + a.y * w3.y + a.z * w3.z + a.w * w3.w;
        }
        qk[c][d0 + 0] = s0;
        qk[c][d0 + 1] = s1;
        qk[c][d0 + 2] = s2;
        qk[c][d0 + 3] = s3;
    }
    __syncthreads();

    if (t < 32) {
        const float tscale = temp[h];
        const float qin = tscale / qn[t];
        float lg[32];
        float mx = -1e30f;
        #pragma unroll
        for (int d = 0; d < 32; ++d) {
            const float l = qk[t][d] * qin / kn[d];
            lg[d] = l;
            mx = fmaxf(mx, l);
        }
        float s = 0.f;
        #pragma unroll
        for (int d = 0; d < 32; ++d) { lg[d] = __expf(lg[d] - mx); s += lg[d]; }
        const float inv = 1.0f / s;
        #pragma unroll
        for (int d = 0; d < 32; ++d) qk[t][d] = lg[d] * inv;
    }
    __syncthreads();

    float accm[32];
    #pragma unroll
    for (int c = 0; c < 32; ++c) accm[c] = 0.f;
    const float* wvp = wqkv + (long)(512 + h * 32) * 256 + t;
    #pragma unroll 4
    for (int d = 0; d < 32; ++d) {
        const float wvv = wvp[(long)d * 256];
        #pragma unroll
        for (int c = 0; c < 32; ++c) accm[c] += qk[c][d] * wvv;
    }
    float* mo = Mout + (long)b * 256 * 256 + (long)(h * 32) * 256 + t;
    #pragma unroll
    for (int c = 0; c < 32; ++c) mo[(long)c * 256] = accm[c];
}

__global__ __launch_bounds__(256) void w2_kernel(
    const float* __restrict__ P, const float* __restrict__ gnb, float* __restrict__ W2)
{
    const int b = blockIdx.x, i = threadIdx.x;
    float e[16];
    float mx = -1e30f;
    #pragma unroll
    for (int c = 0; c < 16; ++c) mx = fmaxf(mx, gnb[c]);
    float s = 0.f;
    #pragma unroll
    for (int c = 0; c < 16; ++c) { e[c] = __expf(gnb[c] - mx); s += e[c]; }
    const float inv = 1.0f / s;
    const float* Pb = P + (long)b * 256 * 256 + i;
    #pragma unroll
    for (int g = 0; g < 16; ++g) {
        float acc = 0.f;
        #pragma unroll
        for (int c = 0; c < 16; ++c) acc += e[c] * Pb[(long)(g * 16 + c) * 256];
        W2[((long)b * 16 + g) * 256 + i] = acc * inv;
    }
}

__global__ __launch_bounds__(256) void wpre_kernel(
    const float* __restrict__ W2, const float* __restrict__ X, float* __restrict__ WP)
{
    __shared__ float w2s[16][260];
    const int b = blockIdx.y;
    const int n = blockIdx.x * 256 + threadIdx.x;
    for (int f = threadIdx.x; f < 16 * 64; f += 256) {
        const int g = f >> 6, c4 = f & 63;
        *(float4*)&w2s[g][c4 * 4] = *(const float4*)(W2 + ((long)b * 16 + g) * 256 + c4 * 4);
    }
    __syncthreads();
    float acc[16] = {};
    const float* xb = X + (long)b * 256 * 4096 + n;
    for (int k = 0; k < 256; ++k) {
        const float xv = xb[(long)k * 4096];
        #pragma unroll
        for (int g = 0; g < 16; ++g) acc[g] += w2s[g][k] * xv;
    }
    #pragma unroll
    for (int g = 0; g < 16; ++g) WP[((long)b * 16 + g) * 4096 + n] = acc[g];
}

// ---------------------------------------------------------------------------
extern "C" void kernel_launch(void* const* d_in, const int* in_sizes, int n_in,
                              void* d_out, int out_size, void* d_ws, size_t ws_size,
                              hipStream_t stream)
{
    const float* x     = (const float*)d_in[0];
    const float* gnb   = (const float*)d_in[4];
    const float* wqkv  = (const float*)d_in[5];
    const float* wproj = (const float*)d_in[6];
    const float* temp  = (const float*)d_in[7];
    float* out = (float*)d_out;

    if (ws_size >= 82051072ULL) {
        // Workspace overlay:
        //  [Xh 32M][pG(8x4M splits) -> Xt 32M][G|Mm 4M][pool: T(8M) -> {P,Ph,W2,WP}]
        char* w = (char*)d_ws;
        _Float16* Xh = (_Float16*)w;
        float*    pG = (float*)(w + 33554432);      // split-K partials (dead after reduce)
        _Float16* Xt = (_Float16*)(w + 33554432);   // overlay: written after reduce
        float*    G  = (float*)(w + 67108864);
        float*    Mm = G;                           // overlay: G dead before attn
        char*     pool = w + 71303168;
        float*    T  = (float*)pool;                // 512x256x16 fp32 = 8MB, dead after attn
        float*    P  = (float*)pool;
        _Float16* Ph = (_Float16*)(pool + 4194304);
        float*    W2 = (float*)(pool + 4194304 + 2097152);
        float*    WP = (float*)(pool + 4194304 + 2097152 + 262144);

        // 1. X -> Xh (f16)
        prep_kernel<<<8192, 256, 0, stream>>>(x, Xh);
        // 2. Gram split-K: 512 workgroups
        gram_split<<<dim3(2, 2, 128), 256, 0, stream>>>(Xh, pG);
        // 3. G = sum of 8 partials (fixed order)
        reduce_g<<<1024, 256, 0, stream>>>(pG, G);
        // 4. Xt = transpose(Xh)  (overwrites dead partials)
        transpose_xt<<<dim3(64, 4, 16), 256, 0, stream>>>(Xh, Xt);
        // 5. T = w_qkv[0:512] @ G_b  (v-rows of T are never consumed)
        gemm64<false, false><<<dim3(4, 8, 16), 256, 0, stream>>>(
            wqkv, G, T, 512, 256, 256, 0L, 65536L, 131072L, nullptr, nullptr);
        // 6. attention in Gram space -> Mm
        attn_kernel<<<128, 256, 0, stream>>>(T, wqkv, temp, Mm, 131072L);
        // 7. P_b = w_proj @ Mm_b
        gemm64<false, false><<<dim3(4, 4, 16), 256, 0, stream>>>(
            wproj, Mm, P, 256, 256, 256, 0L, 65536L, 65536L, nullptr, nullptr);
        // 8. P -> f16
        cvt_half<<<1024, 256, 0, stream>>>(P, Ph);
        // 9. W2 = softmax(gn_b)-weighted group sums of P rows
        w2_kernel<<<16, 256, 0, stream>>>(P, gnb, W2);
        // 10. WP = W2_b @ X_b
        wpre_kernel<<<dim3(16, 16), 256, 0, stream>>>(W2, x, WP);
        // 11. out = Ph_b @ X_b (via Xt) + fused gating epilogue
        out_mfma<<<dim3(32, 2, 16), 256, 0, stream>>>(Ph, Xt, Xh, WP, out);
    } else {
        // Fallback: fp32 path (~30 MB workspace)
        float* ws = (float*)d_ws;
        float* G  = ws;
        float* T  = G  + 16L * 65536;
        float* Mm = T  + 16L * 196608;
        float* P  = Mm + 16L * 65536;
        float* W2 = P  + 16L * 65536;
        float* WP = W2 + 16L * 4096;

        gemm64<true, false><<<dim3(4, 4, 16), 256, 0, stream>>>(
            x, x, G, 256, 256, 4096, 1048576L, 1048576L, 65536L, nullptr, nullptr);
        gemm64<false, false><<<dim3(4, 12, 16), 256, 0, stream>>>(
            wqkv, G, T, 768, 256, 256, 0L, 65536L, 196608L, nullptr, nullptr);
        attn_kernel<<<128, 256, 0, stream>>>(T, wqkv, temp, Mm, 196608L);
        gemm64<false, false><<<dim3(4, 4, 16), 256, 0, stream>>>(
            wproj, Mm, P, 256, 256, 256, 0L, 65536L, 65536L, nullptr, nullptr);
        w2_kernel<<<16, 256, 0, stream>>>(P, gnb, W2);
        wpre_kernel<<<dim3(16, 16), 256, 0, stream>>>(W2, x, WP);
        gemm64<false, true><<<dim3(64, 4, 16), 256, 0, stream>>>(
            P, x, out, 256, 4096, 256, 65536L, 1048576L, 1048576L, x, WP);
    }
}

// Round 5
// 190.789 us; speedup vs baseline: 2.3656x; 1.1277x over previous
//
#include <hip/hip_runtime.h>
#include <math.h>

// Problem constants: B=16, C=256, H=W=64, N=4096, GROUPS=16 (cg=16), HEADS=8 (ch=32)

__device__ __forceinline__ float sigmoidf_(float v) { return 1.0f / (1.0f + __expf(-v)); }

typedef _Float16 half8 __attribute__((ext_vector_type(8)));
typedef _Float16 half4 __attribute__((ext_vector_type(4)));
typedef _Float16 half2v __attribute__((ext_vector_type(2)));
typedef float f32x4 __attribute__((ext_vector_type(4)));

#define GLOAD_LDS16(gp, lp)                                                     \
    __builtin_amdgcn_global_load_lds(                                           \
        (const __attribute__((address_space(1))) void*)(gp),                    \
        (__attribute__((address_space(3))) void*)(lp), 16, 0, 0)

// ---------------------------------------------------------------------------
// Prep: X (fp32) -> Xh (f16 row-major). Pure elementwise, 8 elems/thread.
// ---------------------------------------------------------------------------
__global__ __launch_bounds__(256) void prep_kernel(
    const float* __restrict__ X, _Float16* __restrict__ Xh)
{
    const long i = ((long)blockIdx.x * 256 + threadIdx.x) * 8;
    const float4 v0 = *(const float4*)(X + i);
    const float4 v1 = *(const float4*)(X + i + 4);
    half8 h = { (_Float16)v0.x, (_Float16)v0.y, (_Float16)v0.z, (_Float16)v0.w,
                (_Float16)v1.x, (_Float16)v1.y, (_Float16)v1.z, (_Float16)v1.w };
    *(half8*)(Xh + i) = h;
}

// ---------------------------------------------------------------------------
// Transpose: Xh [b][256][4096] -> Xt [b][4096][256]  (f16, 64x64 LDS tiles)
// Runs AFTER gram reduce (Xt region doubles as split-K partial buffer).
// ---------------------------------------------------------------------------
__global__ __launch_bounds__(256) void transpose_xt(
    const _Float16* __restrict__ Xh, _Float16* __restrict__ Xt)
{
    __shared__ _Float16 tl[64][72];
    const int b = blockIdx.z, c0 = blockIdx.y * 64, n0 = blockIdx.x * 64;
    const int t = threadIdx.x;
    const int r8 = t >> 3, cb = (t & 7) * 8;
    #pragma unroll
    for (int i = 0; i < 2; ++i) {
        const int cc = r8 + 32 * i;
        *(half8*)&tl[cc][cb] =
            *(const half8*)(Xh + ((long)b * 256 + c0 + cc) * 4096 + n0 + cb);
    }
    __syncthreads();
    #pragma unroll
    for (int i = 0; i < 2; ++i) {
        const int nn = r8 + 32 * i;
        half8 v;
        #pragma unroll
        for (int k = 0; k < 8; ++k) v[k] = tl[cb + k][nn];
        *(half8*)(Xt + ((long)b * 4096 + n0 + nn) * 256 + c0 + cb) = v;
    }
}

// ---------------------------------------------------------------------------
// fp32 -> f16 convert (for P)
// ---------------------------------------------------------------------------
__global__ __launch_bounds__(256) void cvt_half(const float* __restrict__ in,
                                                _Float16* __restrict__ o)
{
    const long i = ((long)blockIdx.x * 256 + threadIdx.x) * 4;
    const float4 v = *(const float4*)(in + i);
    half4 h = { (_Float16)v.x, (_Float16)v.y, (_Float16)v.z, (_Float16)v.w };
    *(half4*)(o + i) = h;
}

// ---------------------------------------------------------------------------
// Gram split-K: pG[s][b] = Xh_b[:, s*512:(s+1)*512] . (same)^T
// Slab stride: 16 batches x 65536 floats = 1048576 floats per split (4 MB).
// ---------------------------------------------------------------------------
__global__ __launch_bounds__(256) void gram_split(const _Float16* __restrict__ Xh,
                                                  float* __restrict__ pG)
{
    __shared__ _Float16 Al[128 * 32];
    __shared__ _Float16 Bl[128 * 32];
    const int z = blockIdx.z, b = z >> 3, s = z & 7;
    const int m0 = blockIdx.y * 128, n0 = blockIdx.x * 128;
    const _Float16* Xb = Xh + (long)b * 256 * 4096;
    const int t = threadIdx.x, lane = t & 63, wv = t >> 6;
    const int wm = (wv >> 1) * 64, wn = (wv & 1) * 64;
    f32x4 acc[4][4] = {};

    const int kbeg = s * 512, kend = kbeg + 512;
    for (int k0 = kbeg; k0 < kend; k0 += 32) {
        __syncthreads();
        #pragma unroll
        for (int r = 0; r < 2; ++r) {
            const int e = (r * 256 + t) * 8;
            const int row = e >> 5, col = e & 31;
            GLOAD_LDS16(Xb + (long)(m0 + row) * 4096 + k0 + col, &Al[e]);
            GLOAD_LDS16(Xb + (long)(n0 + row) * 4096 + k0 + col, &Bl[e]);
        }
        __syncthreads();
        half8 af[4], bf[4];
        #pragma unroll
        for (int f = 0; f < 4; ++f) {
            af[f] = *(const half8*)&Al[(wm + f * 16 + (lane & 15)) * 32 + (lane >> 4) * 8];
            bf[f] = *(const half8*)&Bl[(wn + f * 16 + (lane & 15)) * 32 + (lane >> 4) * 8];
        }
        #pragma unroll
        for (int i = 0; i < 4; ++i)
            #pragma unroll
            for (int j = 0; j < 4; ++j)
                acc[i][j] = __builtin_amdgcn_mfma_f32_16x16x32_f16(af[i], bf[j], acc[i][j], 0, 0, 0);
    }
    float* pGb = pG + (long)s * 1048576 + (long)b * 65536;
    #pragma unroll
    for (int i = 0; i < 4; ++i)
        #pragma unroll
        for (int j = 0; j < 4; ++j) {
            const int row = m0 + wm + i * 16 + (lane >> 4) * 4;
            const int col = n0 + wn + j * 16 + (lane & 15);
            float* gp = pGb + (long)row * 256 + col;
            #pragma unroll
            for (int r = 0; r < 4; ++r) gp[(long)r * 256] = acc[i][j][r];
        }
}

// ---------------------------------------------------------------------------
// G = sum_s pG[s]  (fixed order -> deterministic)
// ---------------------------------------------------------------------------
__global__ __launch_bounds__(256) void reduce_g(const float* __restrict__ pG,
                                                float* __restrict__ G)
{
    const long i = ((long)blockIdx.x * 256 + threadIdx.x) * 4;
    f32x4 s = {};
    #pragma unroll
    for (int k = 0; k < 8; ++k) {
        const float4 v = *(const float4*)(pG + (long)k * 1048576 + i);
        s[0] += v.x; s[1] += v.y; s[2] += v.z; s[3] += v.w;
    }
    *(f32x4*)(G + i) = s;
}

// ---------------------------------------------------------------------------
// snorm: Qn[b][r] = T[b][r] . wqkv[r]  for r in [0,512)  (q- and k-norms^2).
// One wave per dot: lane loads one float4 pair, 6-step shfl_xor reduce.
// ---------------------------------------------------------------------------
__global__ __launch_bounds__(256) void snorm_kernel(
    const float* __restrict__ T, const float* __restrict__ wqkv,
    float* __restrict__ Qn)
{
    const int gw = (int)((blockIdx.x * 256 + threadIdx.x) >> 6);  // wave id 0..8191
    const int lane = threadIdx.x & 63;
    const int b = gw >> 9, r = gw & 511;
    const float4 a = *(const float4*)(T + (long)b * 131072 + (long)r * 256 + lane * 4);
    const float4 w = *(const float4*)(wqkv + (long)r * 256 + lane * 4);
    float s = a.x * w.x + a.y * w.y + a.z * w.z + a.w * w.w;
    #pragma unroll
    for (int off = 32; off; off >>= 1) s += __shfl_xor(s, off, 64);
    if (lane == 0) Qn[(long)b * 512 + r] = s;
}

// ---------------------------------------------------------------------------
// attn2: per (b,h): softmax(S1 head-block / (qn kn) * temp) @ Wv_h -> M rows.
// S1 and Mout may alias (reads staged to LDS before any write; blocks touch
// disjoint row ranges).
// ---------------------------------------------------------------------------
__global__ __launch_bounds__(256) void attn2_kernel(
    const float* __restrict__ S1, const float* __restrict__ Qn,
    const float* __restrict__ wqkv, const float* __restrict__ temp,
    float* __restrict__ Mout)
{
    const int bh = blockIdx.x;
    const int b = bh >> 3, h = bh & 7;
    const int t = threadIdx.x;
    __shared__ float pa[32][36];
    __shared__ float qn[32], kn[32];

    {
        const int r = t >> 3, c4 = (t & 7) * 4;
        const float4 v = *(const float4*)(
            S1 + (long)b * 65536 + (long)(h * 32 + r) * 256 + h * 32 + c4);
        pa[r][c4 + 0] = v.x; pa[r][c4 + 1] = v.y;
        pa[r][c4 + 2] = v.z; pa[r][c4 + 3] = v.w;
    }
    if (t < 32)
        qn[t] = fmaxf(sqrtf(Qn[(long)b * 512 + h * 32 + t]), 1e-12f);
    else if (t < 64)
        kn[t - 32] = fmaxf(sqrtf(Qn[(long)b * 512 + 256 + h * 32 + (t - 32)]), 1e-12f);
    __syncthreads();

    if (t < 32) {
        const float qin = temp[h] / qn[t];
        float lg[32];
        float mx = -1e30f;
        #pragma unroll
        for (int d = 0; d < 32; ++d) {
            const float l = pa[t][d] * qin / kn[d];
            lg[d] = l;
            mx = fmaxf(mx, l);
        }
        float s = 0.f;
        #pragma unroll
        for (int d = 0; d < 32; ++d) { lg[d] = __expf(lg[d] - mx); s += lg[d]; }
        const float inv = 1.0f / s;
        #pragma unroll
        for (int d = 0; d < 32; ++d) pa[t][d] = lg[d] * inv;
    }
    __syncthreads();

    float accm[32];
    #pragma unroll
    for (int c = 0; c < 32; ++c) accm[c] = 0.f;
    const float* wvp = wqkv + (long)(512 + h * 32) * 256 + t;
    #pragma unroll 4
    for (int d = 0; d < 32; ++d) {
        const float wvv = wvp[(long)d * 256];
        #pragma unroll
        for (int c = 0; c < 32; ++c) accm[c] += pa[c][d] * wvv;
    }
    float* mo = Mout + (long)b * 65536 + (long)(h * 32) * 256 + t;
    #pragma unroll
    for (int c = 0; c < 32; ++c) mo[(long)c * 256] = accm[c];
}

// ---------------------------------------------------------------------------
// Out: out_b = Ph_b(256x256) @ X_b via Xt rows (K-contiguous), fused epilogue.
// ---------------------------------------------------------------------------
__global__ __launch_bounds__(256) void out_mfma(
    const _Float16* __restrict__ Ph, const _Float16* __restrict__ Xt,
    const _Float16* __restrict__ Xh, const float* __restrict__ WP,
    float* __restrict__ out)
{
    __shared__ _Float16 Al[128 * 32];
    __shared__ _Float16 Bl[128 * 32];
    const int b = blockIdx.z;
    const int m0 = blockIdx.y * 128;   // c
    const int n0 = blockIdx.x * 128;   // n
    const _Float16* Ab = Ph + (long)b * 65536;
    const _Float16* Bb = Xt + (long)b * 1048576;
    const int t = threadIdx.x, lane = t & 63, wv = t >> 6;
    const int wm = (wv >> 1) * 64, wn = (wv & 1) * 64;
    f32x4 acc[4][4] = {};

    for (int k0 = 0; k0 < 256; k0 += 32) {
        __syncthreads();
        #pragma unroll
        for (int r = 0; r < 2; ++r) {
            const int e = (r * 256 + t) * 8;
            const int row = e >> 5, col = e & 31;
            GLOAD_LDS16(Ab + (long)(m0 + row) * 256 + k0 + col, &Al[e]);
            GLOAD_LDS16(Bb + (long)(n0 + row) * 256 + k0 + col, &Bl[e]);
        }
        __syncthreads();
        half8 af[4], bf[4];
        #pragma unroll
        for (int f = 0; f < 4; ++f) {
            af[f] = *(const half8*)&Al[(wm + f * 16 + (lane & 15)) * 32 + (lane >> 4) * 8];
            bf[f] = *(const half8*)&Bl[(wn + f * 16 + (lane & 15)) * 32 + (lane >> 4) * 8];
        }
        #pragma unroll
        for (int i = 0; i < 4; ++i)
            #pragma unroll
            for (int j = 0; j < 4; ++j)
                acc[i][j] = __builtin_amdgcn_mfma_f32_16x16x32_f16(af[i], bf[j], acc[i][j], 0, 0, 0);
    }
    const float* WPb = WP + (long)b * 16 * 4096;
    const _Float16* Xhb = Xh + (long)b * 1048576;
    float* ob = out + (long)b * 1048576;
    #pragma unroll
    for (int i = 0; i < 4; ++i)
        #pragma unroll
        for (int j = 0; j < 4; ++j) {
            const int row0 = m0 + wm + i * 16 + (lane >> 4) * 4;
            const int col = n0 + wn + j * 16 + (lane & 15);
            #pragma unroll
            for (int r = 0; r < 4; ++r) {
                const int c = row0 + r;
                const float xv = (float)Xhb[(long)c * 4096 + col];
                const float wpv = WPb[(long)(c >> 4) * 4096 + col];
                ob[(long)c * 4096 + col] = xv * sigmoidf_(wpv) + acc[i][j][r];
            }
        }
}

// ---------------------------------------------------------------------------
// Generic 64x64-tile fp32 GEMM (small GEMMs + fallback path).
// ---------------------------------------------------------------------------
template <bool BT, bool EPI>
__global__ __launch_bounds__(256) void gemm64(
    const float* __restrict__ A, const float* __restrict__ B, float* __restrict__ C,
    int M, int N, int K, long sA, long sB, long sC,
    const float* __restrict__ X, const float* __restrict__ WP)
{
    __shared__ float As[32][68];
    __shared__ float Bs[32][68];
    const int b = blockIdx.z;
    const float* Ab = A + (long)b * sA;
    const float* Bb = B + (long)b * sB;
    float* Cb = C + (long)b * sC;
    const int t = threadIdx.x;
    const int tx = t & 15, ty = t >> 4;
    const int m0 = blockIdx.y * 64, n0 = blockIdx.x * 64;

    float acc[4][4] = {};

    for (int k0 = 0; k0 < K; k0 += 32) {
        __syncthreads();
        #pragma unroll
        for (int f0 = 0; f0 < 512; f0 += 256) {
            const int f = f0 + t;
            const int row = f >> 3, c4 = f & 7;
            const float4 v = *(const float4*)(Ab + (long)(m0 + row) * K + k0 + c4 * 4);
            As[c4 * 4 + 0][row] = v.x;
            As[c4 * 4 + 1][row] = v.y;
            As[c4 * 4 + 2][row] = v.z;
            As[c4 * 4 + 3][row] = v.w;
        }
        if (BT) {
            #pragma unroll
            for (int f0 = 0; f0 < 512; f0 += 256) {
                const int f = f0 + t;
                const int row = f >> 3, c4 = f & 7;
                const float4 v = *(const float4*)(Bb + (long)(n0 + row) * K + k0 + c4 * 4);
                Bs[c4 * 4 + 0][row] = v.x;
                Bs[c4 * 4 + 1][row] = v.y;
                Bs[c4 * 4 + 2][row] = v.z;
                Bs[c4 * 4 + 3][row] = v.w;
            }
        } else {
            #pragma unroll
            for (int f0 = 0; f0 < 512; f0 += 256) {
                const int f = f0 + t;
                const int kk = f >> 4, c4 = f & 15;
                *(float4*)&Bs[kk][c4 * 4] =
                    *(const float4*)(Bb + (long)(k0 + kk) * N + n0 + c4 * 4);
            }
        }
        __syncthreads();
        #pragma unroll
        for (int kk = 0; kk < 32; ++kk) {
            const float4 av = *(const float4*)&As[kk][ty * 4];
            const float4 bv = *(const float4*)&Bs[kk][tx * 4];
            const float a0 = av.x, a1 = av.y, a2 = av.z, a3 = av.w;
            const float b0 = bv.x, b1 = bv.y, b2 = bv.z, b3 = bv.w;
            acc[0][0] += a0 * b0; acc[0][1] += a0 * b1; acc[0][2] += a0 * b2; acc[0][3] += a0 * b3;
            acc[1][0] += a1 * b0; acc[1][1] += a1 * b1; acc[1][2] += a1 * b2; acc[1][3] += a1 * b3;
            acc[2][0] += a2 * b0; acc[2][1] += a2 * b1; acc[2][2] += a2 * b2; acc[2][3] += a2 * b3;
            acc[3][0] += a3 * b0; acc[3][1] += a3 * b1; acc[3][2] += a3 * b2; acc[3][3] += a3 * b3;
        }
    }

    if (EPI) {
        #pragma unroll
        for (int i = 0; i < 4; ++i) {
            const int c = m0 + ty * 4 + i;
            const long nidx = n0 + tx * 4;
            const float4 xv = *(const float4*)(X + ((long)b * 256 + c) * 4096 + nidx);
            const float4 wv = *(const float4*)(WP + ((long)b * 16 + (c >> 4)) * 4096 + nidx);
            float4 o;
            o.x = xv.x * sigmoidf_(wv.x) + acc[i][0];
            o.y = xv.y * sigmoidf_(wv.y) + acc[i][1];
            o.z = xv.z * sigmoidf_(wv.z) + acc[i][2];
            o.w = xv.w * sigmoidf_(wv.w) + acc[i][3];
            *(float4*)(Cb + (long)c * N + nidx) = o;
        }
    } else {
        #pragma unroll
        for (int i = 0; i < 4; ++i) {
            const float4 o = make_float4(acc[i][0], acc[i][1], acc[i][2], acc[i][3]);
            *(float4*)(Cb + (long)(m0 + ty * 4 + i) * N + n0 + tx * 4) = o;
        }
    }
}

// ---------------------------------------------------------------------------
// Per-(b,h) attention in Gram space (fallback path only).
// ---------------------------------------------------------------------------
__global__ __launch_bounds__(256) void attn_kernel(
    const float* __restrict__ T, const float* __restrict__ wqkv,
    const float* __restrict__ temp, float* __restrict__ Mout, long tStride)
{
    const int bh = blockIdx.x;
    const int b = bh >> 3, h = bh & 7;
    const int t = threadIdx.x;
    __shared__ float Tq[32][260];
    __shared__ float qk[32][33];
    __shared__ float qn[32], kn[32];
    const float* Tb = T + (long)b * tStride;

    for (int f = t; f < 32 * 64; f += 256) {
        const int r = f >> 6, c4 = f & 63;
        *(float4*)&Tq[r][c4 * 4] = *(const float4*)(Tb + (long)(h * 32 + r) * 256 + c4 * 4);
    }
    __syncthreads();

    if (t < 32) {
        float s = 0.f;
        const float* wq = wqkv + (long)(h * 32 + t) * 256;
        #pragma unroll 4
        for (int k = 0; k < 256; k += 4) {
            const float4 a = *(const float4*)&Tq[t][k];
            const float4 w = *(const float4*)(wq + k);
            s += a.x * w.x + a.y * w.y + a.z * w.z + a.w * w.w;
        }
        qn[t] = fmaxf(sqrtf(s), 1e-12f);
    } else if (t < 64) {
        const int d = t - 32;
        float s = 0.f;
        const float* tk = Tb + (long)(256 + h * 32 + d) * 256;
        const float* wk = wqkv + (long)(256 + h * 32 + d) * 256;
        #pragma unroll 4
        for (int k = 0; k < 256; k += 4) {
            const float4 a = *(const float4*)(tk + k);
            const float4 w = *(const float4*)(wk + k);
            s += a.x * w.x + a.y * w.y + a.z * w.z + a.w * w.w;
        }
        kn[d] = fmaxf(sqrtf(s), 1e-12f);
    }

    {
        const int c = t >> 3, d0 = (t & 7) * 4;
        float s0 = 0, s1 = 0, s2 = 0, s3 = 0;
        const float* wk0 = wqkv + (long)(256 + h * 32 + d0) * 256;
        #pragma unroll 4
        for (int k = 0; k < 256; k += 4) {
            const float4 a = *(const float4*)&Tq[c][k];
            const float4 w0 = *(const float4*)(wk0 + k);
            const float4 w1 = *(const float4*)(wk0 + 256 + k);
            const float4 w2 = *(const float4*)(wk0 + 512 + k);
            const float4 w3 = *(const float4*)(wk0 + 768 + k);
            s0 += a.x * w0.x + a.y * w0.y + a.z * w0.z + a.w * w0.w;
            s1 += a.x * w1.x + a.y * w1.y + a.z * w1.z + a.w * w1.w;
            s2 += a.x * w2.x + a.y * w2.y + a.z * w2.z + a.w * w2.w;
            s3 += a.x * w3.x + a.y * w3.y + a.z * w3.z + a.w * w3.w;
        }
        qk[c][d0 + 0] = s0;
        qk[c][d0 + 1] = s1;
        qk[c][d0 + 2] = s2;
        qk[c][d0 + 3] = s3;
    }
    __syncthreads();

    if (t < 32) {
        const float tscale = temp[h];
        const float qin = tscale / qn[t];
        float lg[32];
        float mx = -1e30f;
        #pragma unroll
        for (int d = 0; d < 32; ++d) {
            const float l = qk[t][d] * qin / kn[d];
            lg[d] = l;
            mx = fmaxf(mx, l);
        }
        float s = 0.f;
        #pragma unroll
        for (int d = 0; d < 32; ++d) { lg[d] = __expf(lg[d] - mx); s += lg[d]; }
        const float inv = 1.0f / s;
        #pragma unroll
        for (int d = 0; d < 32; ++d) qk[t][d] = lg[d] * inv;
    }
    __syncthreads();

    float accm[32];
    #pragma unroll
    for (int c = 0; c < 32; ++c) accm[c] = 0.f;
    const float* wvp = wqkv + (long)(512 + h * 32) * 256 + t;
    #pragma unroll 4
    for (int d = 0; d < 32; ++d) {
        const float wvv = wvp[(long)d * 256];
        #pragma unroll
        for (int c = 0; c < 32; ++c) accm[c] += qk[c][d] * wvv;
    }
    float* mo = Mout + (long)b * 256 * 256 + (long)(h * 32) * 256 + t;
    #pragma unroll
    for (int c = 0; c < 32; ++c) mo[(long)c * 256] = accm[c];
}

__global__ __launch_bounds__(256) void w2_kernel(
    const float* __restrict__ P, const float* __restrict__ gnb, float* __restrict__ W2)
{
    const int b = blockIdx.x, i = threadIdx.x;
    float e[16];
    float mx = -1e30f;
    #pragma unroll
    for (int c = 0; c < 16; ++c) mx = fmaxf(mx, gnb[c]);
    float s = 0.f;
    #pragma unroll
    for (int c = 0; c < 16; ++c) { e[c] = __expf(gnb[c] - mx); s += e[c]; }
    const float inv = 1.0f / s;
    const float* Pb = P + (long)b * 256 * 256 + i;
    #pragma unroll
    for (int g = 0; g < 16; ++g) {
        float acc = 0.f;
        #pragma unroll
        for (int c = 0; c < 16; ++c) acc += e[c] * Pb[(long)(g * 16 + c) * 256];
        W2[((long)b * 16 + g) * 256 + i] = acc * inv;
    }
}

__global__ __launch_bounds__(256) void wpre_kernel(
    const float* __restrict__ W2, const float* __restrict__ X, float* __restrict__ WP)
{
    __shared__ float w2s[16][260];
    const int b = blockIdx.y;
    const int n = blockIdx.x * 256 + threadIdx.x;
    for (int f = threadIdx.x; f < 16 * 64; f += 256) {
        const int g = f >> 6, c4 = f & 63;
        *(float4*)&w2s[g][c4 * 4] = *(const float4*)(W2 + ((long)b * 16 + g) * 256 + c4 * 4);
    }
    __syncthreads();
    float acc[16] = {};
    const float* xb = X + (long)b * 256 * 4096 + n;
    for (int k = 0; k < 256; ++k) {
        const float xv = xb[(long)k * 4096];
        #pragma unroll
        for (int g = 0; g < 16; ++g) acc[g] += w2s[g][k] * xv;
    }
    #pragma unroll
    for (int g = 0; g < 16; ++g) WP[((long)b * 16 + g) * 4096 + n] = acc[g];
}

// ---------------------------------------------------------------------------
extern "C" void kernel_launch(void* const* d_in, const int* in_sizes, int n_in,
                              void* d_out, int out_size, void* d_ws, size_t ws_size,
                              hipStream_t stream)
{
    const float* x     = (const float*)d_in[0];
    const float* gnb   = (const float*)d_in[4];
    const float* wqkv  = (const float*)d_in[5];
    const float* wproj = (const float*)d_in[6];
    const float* temp  = (const float*)d_in[7];
    float* out = (float*)d_out;

    if (ws_size >= 82051072ULL) {
        // Workspace overlay:
        //  [Xh 32M][pG(8x4M) -> Xt 32M][G -> S1 -> Mm 4M][pool: {T 8M, Qn 32K} -> {P,Ph,W2,WP}]
        char* w = (char*)d_ws;
        _Float16* Xh = (_Float16*)w;
        float*    pG = (float*)(w + 33554432);      // split-K partials (dead after reduce)
        _Float16* Xt = (_Float16*)(w + 33554432);   // overlay: written after reduce
        float*    G  = (float*)(w + 67108864);
        float*    S1 = G;                           // overlay: G dead after T-gemm
        float*    Mm = G;                           // overlay: attn2 stages S1 reads in LDS
        char*     pool = w + 71303168;
        float*    T  = (float*)pool;                // 512x256x16 fp32 = 8MB
        float*    Qn = (float*)(pool + 8388608);    // 32KB norms^2
        float*    P  = (float*)pool;                // overwrites dead T
        _Float16* Ph = (_Float16*)(pool + 4194304);
        float*    W2 = (float*)(pool + 4194304 + 2097152);
        float*    WP = (float*)(pool + 4194304 + 2097152 + 262144);

        // 1. X -> Xh (f16)
        prep_kernel<<<8192, 256, 0, stream>>>(x, Xh);
        // 2. Gram split-K: 512 workgroups
        gram_split<<<dim3(2, 2, 128), 256, 0, stream>>>(Xh, pG);
        // 3. G = sum of 8 partials (fixed order)
        reduce_g<<<1024, 256, 0, stream>>>(pG, G);
        // 4. Xt = transpose(Xh)  (overwrites dead partials)
        transpose_xt<<<dim3(64, 4, 16), 256, 0, stream>>>(Xh, Xt);
        // 5. T = w_qkv[0:512] @ G_b
        gemm64<false, false><<<dim3(4, 8, 16), 256, 0, stream>>>(
            wqkv, G, T, 512, 256, 256, 0L, 65536L, 131072L, nullptr, nullptr);
        // 6. Qn[b][r] = T[b][r].wqkv[r]  (q/k norms^2, one wave per dot)
        snorm_kernel<<<2048, 256, 0, stream>>>(T, wqkv, Qn);
        // 7. S1 = Tq @ Wk^T  (raw logits, all head pairs; overlays dead G)
        gemm64<true, false><<<dim3(4, 4, 16), 256, 0, stream>>>(
            T, wqkv + 65536, S1, 256, 256, 256, 131072L, 0L, 65536L, nullptr, nullptr);
        // 8. softmax + @Wv per (b,h) -> Mm (aliases S1; LDS-staged)
        attn2_kernel<<<128, 256, 0, stream>>>(S1, Qn, wqkv, temp, Mm);
        // 9. P_b = w_proj @ Mm_b  (overwrites dead T)
        gemm64<false, false><<<dim3(4, 4, 16), 256, 0, stream>>>(
            wproj, Mm, P, 256, 256, 256, 0L, 65536L, 65536L, nullptr, nullptr);
        // 10. P -> f16
        cvt_half<<<1024, 256, 0, stream>>>(P, Ph);
        // 11. W2 = softmax(gn_b)-weighted group sums of P rows
        w2_kernel<<<16, 256, 0, stream>>>(P, gnb, W2);
        // 12. WP = W2_b @ X_b
        wpre_kernel<<<dim3(16, 16), 256, 0, stream>>>(W2, x, WP);
        // 13. out = Ph_b @ X_b (via Xt) + fused gating epilogue
        out_mfma<<<dim3(32, 2, 16), 256, 0, stream>>>(Ph, Xt, Xh, WP, out);
    } else {
        // Fallback: fp32 path (~30 MB workspace)
        float* ws = (float*)d_ws;
        float* G  = ws;
        float* T  = G  + 16L * 65536;
        float* Mm = T  + 16L * 196608;
        float* P  = Mm + 16L * 65536;
        float* W2 = P  + 16L * 65536;
        float* WP = W2 + 16L * 4096;

        gemm64<true, false><<<dim3(4, 4, 16), 256, 0, stream>>>(
            x, x, G, 256, 256, 4096, 1048576L, 1048576L, 65536L, nullptr, nullptr);
        gemm64<false, false><<<dim3(4, 12, 16), 256, 0, stream>>>(
            wqkv, G, T, 768, 256, 256, 0L, 65536L, 196608L, nullptr, nullptr);
        attn_kernel<<<128, 256, 0, stream>>>(T, wqkv, temp, Mm, 196608L);
        gemm64<false, false><<<dim3(4, 4, 16), 256, 0, stream>>>(
            wproj, Mm, P, 256, 256, 256, 0L, 65536L, 65536L, nullptr, nullptr);
        w2_kernel<<<16, 256, 0, stream>>>(P, gnb, W2);
        wpre_kernel<<<dim3(16, 16), 256, 0, stream>>>(W2, x, WP);
        gemm64<false, true><<<dim3(64, 4, 16), 256, 0, stream>>>(
            P, x, out, 256, 4096, 256, 65536L, 1048576L, 1048576L, x, WP);
    }
}

// Round 6
// 158.721 us; speedup vs baseline: 2.8435x; 1.2020x over previous
//
#include <hip/hip_runtime.h>
#include <math.h>

// Problem constants: B=16, C=256, H=W=64, N=4096, GROUPS=16 (cg=16), HEADS=8 (ch=32)

__device__ __forceinline__ float sigmoidf_(float v) { return 1.0f / (1.0f + __expf(-v)); }

typedef _Float16 half8 __attribute__((ext_vector_type(8)));
typedef _Float16 half4 __attribute__((ext_vector_type(4)));
typedef float f32x4 __attribute__((ext_vector_type(4)));

#define GLOAD_LDS16(gp, lp)                                                     \
    __builtin_amdgcn_global_load_lds(                                           \
        (const __attribute__((address_space(1))) void*)(gp),                    \
        (__attribute__((address_space(3))) void*)(lp), 16, 0, 0)

// ---------------------------------------------------------------------------
// prep_fused: X (fp32 [b][256][4096]) -> Xh (f16 row-major) + Xt (f16 [b][4096][256])
// One pass: 64x64 fp32 LDS tile for the transpose. 128 MB total traffic.
// ---------------------------------------------------------------------------
__global__ __launch_bounds__(256) void prep_fused(
    const float* __restrict__ X, _Float16* __restrict__ Xh, _Float16* __restrict__ Xt)
{
    __shared__ float tl[64][68];
    const int b = blockIdx.z, c0 = blockIdx.y * 64, n0 = blockIdx.x * 64;
    const int t = threadIdx.x;
    const int r0 = t >> 4;          // 0..15
    const int q = (t & 15) * 4;     // col 0..60
    const float* Xb = X + ((long)b * 256 + c0) * 4096 + n0;
    _Float16* Xhb = Xh + ((long)b * 256 + c0) * 4096 + n0;
    #pragma unroll
    for (int i = 0; i < 4; ++i) {
        const int r = r0 + i * 16;
        const float4 v = *(const float4*)(Xb + (long)r * 4096 + q);
        tl[r][q + 0] = v.x; tl[r][q + 1] = v.y;
        tl[r][q + 2] = v.z; tl[r][q + 3] = v.w;
        half4 h = { (_Float16)v.x, (_Float16)v.y, (_Float16)v.z, (_Float16)v.w };
        *(half4*)(Xhb + (long)r * 4096 + q) = h;
    }
    __syncthreads();
    const int nn = t >> 2, cc = (t & 3) * 16;
    _Float16* Xtb = Xt + ((long)b * 4096 + n0 + nn) * 256 + c0 + cc;
    half8 o0, o1;
    #pragma unroll
    for (int k = 0; k < 8; ++k) o0[k] = (_Float16)tl[cc + k][nn];
    #pragma unroll
    for (int k = 0; k < 8; ++k) o1[k] = (_Float16)tl[cc + 8 + k][nn];
    *(half8*)(Xtb) = o0;
    *(half8*)(Xtb + 8) = o1;
}

// ---------------------------------------------------------------------------
// fp32 -> f16 convert (for P)
// ---------------------------------------------------------------------------
__global__ __launch_bounds__(256) void cvt_half(const float* __restrict__ in,
                                                _Float16* __restrict__ o)
{
    const long i = ((long)blockIdx.x * 256 + threadIdx.x) * 4;
    const float4 v = *(const float4*)(in + i);
    half4 h = { (_Float16)v.x, (_Float16)v.y, (_Float16)v.z, (_Float16)v.w };
    *(half4*)(o + i) = h;
}

// ---------------------------------------------------------------------------
// Gram split-K: pG[s][b] = Xh_b[:, s*512:(s+1)*512] . (same)^T
// pG lives in d_out (64 MB fp32, dead until out_fused fully overwrites it).
// Slab stride: 16 batches x 65536 floats = 1048576 floats per split (4 MB).
// ---------------------------------------------------------------------------
__global__ __launch_bounds__(256) void gram_split(const _Float16* __restrict__ Xh,
                                                  float* __restrict__ pG)
{
    __shared__ _Float16 Al[128 * 32];
    __shared__ _Float16 Bl[128 * 32];
    const int z = blockIdx.z, b = z >> 3, s = z & 7;
    const int m0 = blockIdx.y * 128, n0 = blockIdx.x * 128;
    const _Float16* Xb = Xh + (long)b * 256 * 4096;
    const int t = threadIdx.x, lane = t & 63, wv = t >> 6;
    const int wm = (wv >> 1) * 64, wn = (wv & 1) * 64;
    f32x4 acc[4][4] = {};

    const int kbeg = s * 512, kend = kbeg + 512;
    for (int k0 = kbeg; k0 < kend; k0 += 32) {
        __syncthreads();
        #pragma unroll
        for (int r = 0; r < 2; ++r) {
            const int e = (r * 256 + t) * 8;
            const int row = e >> 5, col = e & 31;
            GLOAD_LDS16(Xb + (long)(m0 + row) * 4096 + k0 + col, &Al[e]);
            GLOAD_LDS16(Xb + (long)(n0 + row) * 4096 + k0 + col, &Bl[e]);
        }
        __syncthreads();
        half8 af[4], bf[4];
        #pragma unroll
        for (int f = 0; f < 4; ++f) {
            af[f] = *(const half8*)&Al[(wm + f * 16 + (lane & 15)) * 32 + (lane >> 4) * 8];
            bf[f] = *(const half8*)&Bl[(wn + f * 16 + (lane & 15)) * 32 + (lane >> 4) * 8];
        }
        #pragma unroll
        for (int i = 0; i < 4; ++i)
            #pragma unroll
            for (int j = 0; j < 4; ++j)
                acc[i][j] = __builtin_amdgcn_mfma_f32_16x16x32_f16(af[i], bf[j], acc[i][j], 0, 0, 0);
    }
    float* pGb = pG + (long)s * 1048576 + (long)b * 65536;
    #pragma unroll
    for (int i = 0; i < 4; ++i)
        #pragma unroll
        for (int j = 0; j < 4; ++j) {
            const int row = m0 + wm + i * 16 + (lane >> 4) * 4;
            const int col = n0 + wn + j * 16 + (lane & 15);
            float* gp = pGb + (long)row * 256 + col;
            #pragma unroll
            for (int r = 0; r < 4; ++r) gp[(long)r * 256] = acc[i][j][r];
        }
}

// ---------------------------------------------------------------------------
// G = sum_s pG[s]  (fixed order -> deterministic)
// ---------------------------------------------------------------------------
__global__ __launch_bounds__(256) void reduce_g(const float* __restrict__ pG,
                                                float* __restrict__ G)
{
    const long i = ((long)blockIdx.x * 256 + threadIdx.x) * 4;
    f32x4 s = {};
    #pragma unroll
    for (int k = 0; k < 8; ++k) {
        const float4 v = *(const float4*)(pG + (long)k * 1048576 + i);
        s[0] += v.x; s[1] += v.y; s[2] += v.z; s[3] += v.w;
    }
    *(f32x4*)(G + i) = s;
}

// ---------------------------------------------------------------------------
// snorm: Qn[b][r] = T[b][r] . wqkv[r]  for r in [0,512)  (q/k norms^2).
// ---------------------------------------------------------------------------
__global__ __launch_bounds__(256) void snorm_kernel(
    const float* __restrict__ T, const float* __restrict__ wqkv,
    float* __restrict__ Qn)
{
    const int gw = (int)((blockIdx.x * 256 + threadIdx.x) >> 6);
    const int lane = threadIdx.x & 63;
    const int b = gw >> 9, r = gw & 511;
    const float4 a = *(const float4*)(T + (long)b * 131072 + (long)r * 256 + lane * 4);
    const float4 w = *(const float4*)(wqkv + (long)r * 256 + lane * 4);
    float s = a.x * w.x + a.y * w.y + a.z * w.z + a.w * w.w;
    #pragma unroll
    for (int off = 32; off; off >>= 1) s += __shfl_xor(s, off, 64);
    if (lane == 0) Qn[(long)b * 512 + r] = s;
}

// ---------------------------------------------------------------------------
// attn2: per (b,h): softmax(S1 head-block / (qn kn) * temp) @ Wv_h -> M rows.
// S1 and Mout alias (tile staged to LDS first; blocks touch disjoint rows).
// ---------------------------------------------------------------------------
__global__ __launch_bounds__(256) void attn2_kernel(
    const float* __restrict__ S1, const float* __restrict__ Qn,
    const float* __restrict__ wqkv, const float* __restrict__ temp,
    float* __restrict__ Mout)
{
    const int bh = blockIdx.x;
    const int b = bh >> 3, h = bh & 7;
    const int t = threadIdx.x;
    __shared__ float pa[32][36];
    __shared__ float qn[32], kn[32];

    {
        const int r = t >> 3, c4 = (t & 7) * 4;
        const float4 v = *(const float4*)(
            S1 + (long)b * 65536 + (long)(h * 32 + r) * 256 + h * 32 + c4);
        pa[r][c4 + 0] = v.x; pa[r][c4 + 1] = v.y;
        pa[r][c4 + 2] = v.z; pa[r][c4 + 3] = v.w;
    }
    if (t < 32)
        qn[t] = fmaxf(sqrtf(Qn[(long)b * 512 + h * 32 + t]), 1e-12f);
    else if (t < 64)
        kn[t - 32] = fmaxf(sqrtf(Qn[(long)b * 512 + 256 + h * 32 + (t - 32)]), 1e-12f);
    __syncthreads();

    if (t < 32) {
        const float qin = temp[h] / qn[t];
        float lg[32];
        float mx = -1e30f;
        #pragma unroll
        for (int d = 0; d < 32; ++d) {
            const float l = pa[t][d] * qin / kn[d];
            lg[d] = l;
            mx = fmaxf(mx, l);
        }
        float s = 0.f;
        #pragma unroll
        for (int d = 0; d < 32; ++d) { lg[d] = __expf(lg[d] - mx); s += lg[d]; }
        const float inv = 1.0f / s;
        #pragma unroll
        for (int d = 0; d < 32; ++d) pa[t][d] = lg[d] * inv;
    }
    __syncthreads();

    float accm[32];
    #pragma unroll
    for (int c = 0; c < 32; ++c) accm[c] = 0.f;
    const float* wvp = wqkv + (long)(512 + h * 32) * 256 + t;
    #pragma unroll 4
    for (int d = 0; d < 32; ++d) {
        const float wvv = wvp[(long)d * 256];
        #pragma unroll
        for (int c = 0; c < 32; ++c) accm[c] += pa[c][d] * wvv;
    }
    float* mo = Mout + (long)b * 65536 + (long)(h * 32) * 256 + t;
    #pragma unroll
    for (int c = 0; c < 32; ++c) mo[(long)c * 256] = accm[c];
}

// ---------------------------------------------------------------------------
// out_fused: out_b = Ph_b @ X_b (via Xt) with:
//  - fused S2 = W2h @ X_b via one extra 16-row A-fragment (kills wpre/WP),
//  - LDS-staged vectorized epilogue: y = Xh*sigmoid(S2) + acc, float4 stores.
// LDS: smem (Al+Bl during K loop, reused as 64x132 fp32 C-stage) + S2l.
// ---------------------------------------------------------------------------
__global__ __launch_bounds__(256) void out_fused(
    const _Float16* __restrict__ Ph, const _Float16* __restrict__ Xt,
    const _Float16* __restrict__ Xh, const _Float16* __restrict__ W2h,
    float* __restrict__ out)
{
    __shared__ __align__(16) char smem[64 * 132 * 4];   // 33792 B
    __shared__ float S2l[16][132];                      // 8448 B
    _Float16* Al = (_Float16*)smem;
    _Float16* Bl = (_Float16*)(smem + 8192);
    float (*cst)[132] = (float(*)[132])smem;

    const int b = blockIdx.z;
    const int m0 = blockIdx.y * 128, n0 = blockIdx.x * 128;
    const _Float16* Ab = Ph + (long)b * 65536;
    const _Float16* Bb = Xt + (long)b * 1048576;
    const _Float16* W2b = W2h + (long)b * 4096;
    const int t = threadIdx.x, lane = t & 63, wv = t >> 6;
    const int wm = (wv >> 1) * 64, wn = (wv & 1) * 64;

    f32x4 acc[4][4] = {};
    f32x4 s2acc[4] = {};

    for (int k0 = 0; k0 < 256; k0 += 32) {
        __syncthreads();
        // W2 A-fragment for this k-step (L2-hot, hidden under staging)
        const half8 wf = *(const half8*)(W2b + (long)(lane & 15) * 256 + k0 + (lane >> 4) * 8);
        #pragma unroll
        for (int r = 0; r < 2; ++r) {
            const int e = (r * 256 + t) * 8;
            const int row = e >> 5, col = e & 31;
            GLOAD_LDS16(Ab + (long)(m0 + row) * 256 + k0 + col, &Al[e]);
            GLOAD_LDS16(Bb + (long)(n0 + row) * 256 + k0 + col, &Bl[e]);
        }
        __syncthreads();
        half8 af[4], bf[4];
        #pragma unroll
        for (int f = 0; f < 4; ++f) {
            af[f] = *(const half8*)&Al[(wm + f * 16 + (lane & 15)) * 32 + (lane >> 4) * 8];
            bf[f] = *(const half8*)&Bl[(wn + f * 16 + (lane & 15)) * 32 + (lane >> 4) * 8];
        }
        #pragma unroll
        for (int i = 0; i < 4; ++i)
            #pragma unroll
            for (int j = 0; j < 4; ++j)
                acc[i][j] = __builtin_amdgcn_mfma_f32_16x16x32_f16(af[i], bf[j], acc[i][j], 0, 0, 0);
        #pragma unroll
        for (int j = 0; j < 4; ++j)
            s2acc[j] = __builtin_amdgcn_mfma_f32_16x16x32_f16(wf, bf[j], s2acc[j], 0, 0, 0);
    }

    __syncthreads();   // Al/Bl dead; smem becomes cst
    // S2 -> LDS (wm==0 waves; wm==64 duplicates would write identical values)
    if (wm == 0) {
        #pragma unroll
        for (int j = 0; j < 4; ++j)
            #pragma unroll
            for (int r = 0; r < 4; ++r)
                S2l[(lane >> 4) * 4 + r][wn + j * 16 + (lane & 15)] = s2acc[j][r];
    }

    const _Float16* Xhb = Xh + (long)b * 1048576;
    float* ob = out + (long)b * 1048576;

    #pragma unroll
    for (int hf = 0; hf < 2; ++hf) {
        if (wm == hf * 64) {
            #pragma unroll
            for (int i = 0; i < 4; ++i)
                #pragma unroll
                for (int j = 0; j < 4; ++j)
                    #pragma unroll
                    for (int r = 0; r < 4; ++r)
                        cst[i * 16 + (lane >> 4) * 4 + r][wn + j * 16 + (lane & 15)] = acc[i][j][r];
        }
        __syncthreads();
        #pragma unroll
        for (int it = 0; it < 8; ++it) {
            const int row = it * 8 + (t >> 5);
            const int col = (t & 31) * 4;
            const int c = m0 + hf * 64 + row;
            const float4 v = *(const float4*)&cst[row][col];
            const float4 s2 = *(const float4*)&S2l[c >> 4][col];
            const half4 xv = *(const half4*)(Xhb + (long)c * 4096 + n0 + col);
            float4 o;
            o.x = (float)xv[0] * sigmoidf_(s2.x) + v.x;
            o.y = (float)xv[1] * sigmoidf_(s2.y) + v.y;
            o.z = (float)xv[2] * sigmoidf_(s2.z) + v.z;
            o.w = (float)xv[3] * sigmoidf_(s2.w) + v.w;
            *(float4*)(ob + (long)c * 4096 + n0 + col) = o;
        }
        __syncthreads();
    }
}

// ---------------------------------------------------------------------------
// Generic 64x64-tile fp32 GEMM (small GEMMs + fallback path).
// ---------------------------------------------------------------------------
template <bool BT, bool EPI>
__global__ __launch_bounds__(256) void gemm64(
    const float* __restrict__ A, const float* __restrict__ B, float* __restrict__ C,
    int M, int N, int K, long sA, long sB, long sC,
    const float* __restrict__ X, const float* __restrict__ WP)
{
    __shared__ float As[32][68];
    __shared__ float Bs[32][68];
    const int b = blockIdx.z;
    const float* Ab = A + (long)b * sA;
    const float* Bb = B + (long)b * sB;
    float* Cb = C + (long)b * sC;
    const int t = threadIdx.x;
    const int tx = t & 15, ty = t >> 4;
    const int m0 = blockIdx.y * 64, n0 = blockIdx.x * 64;

    float acc[4][4] = {};

    for (int k0 = 0; k0 < K; k0 += 32) {
        __syncthreads();
        #pragma unroll
        for (int f0 = 0; f0 < 512; f0 += 256) {
            const int f = f0 + t;
            const int row = f >> 3, c4 = f & 7;
            const float4 v = *(const float4*)(Ab + (long)(m0 + row) * K + k0 + c4 * 4);
            As[c4 * 4 + 0][row] = v.x;
            As[c4 * 4 + 1][row] = v.y;
            As[c4 * 4 + 2][row] = v.z;
            As[c4 * 4 + 3][row] = v.w;
        }
        if (BT) {
            #pragma unroll
            for (int f0 = 0; f0 < 512; f0 += 256) {
                const int f = f0 + t;
                const int row = f >> 3, c4 = f & 7;
                const float4 v = *(const float4*)(Bb + (long)(n0 + row) * K + k0 + c4 * 4);
                Bs[c4 * 4 + 0][row] = v.x;
                Bs[c4 * 4 + 1][row] = v.y;
                Bs[c4 * 4 + 2][row] = v.z;
                Bs[c4 * 4 + 3][row] = v.w;
            }
        } else {
            #pragma unroll
            for (int f0 = 0; f0 < 512; f0 += 256) {
                const int f = f0 + t;
                const int kk = f >> 4, c4 = f & 15;
                *(float4*)&Bs[kk][c4 * 4] =
                    *(const float4*)(Bb + (long)(k0 + kk) * N + n0 + c4 * 4);
            }
        }
        __syncthreads();
        #pragma unroll
        for (int kk = 0; kk < 32; ++kk) {
            const float4 av = *(const float4*)&As[kk][ty * 4];
            const float4 bv = *(const float4*)&Bs[kk][tx * 4];
            const float a0 = av.x, a1 = av.y, a2 = av.z, a3 = av.w;
            const float b0 = bv.x, b1 = bv.y, b2 = bv.z, b3 = bv.w;
            acc[0][0] += a0 * b0; acc[0][1] += a0 * b1; acc[0][2] += a0 * b2; acc[0][3] += a0 * b3;
            acc[1][0] += a1 * b0; acc[1][1] += a1 * b1; acc[1][2] += a1 * b2; acc[1][3] += a1 * b3;
            acc[2][0] += a2 * b0; acc[2][1] += a2 * b1; acc[2][2] += a2 * b2; acc[2][3] += a2 * b3;
            acc[3][0] += a3 * b0; acc[3][1] += a3 * b1; acc[3][2] += a3 * b2; acc[3][3] += a3 * b3;
        }
    }

    if (EPI) {
        #pragma unroll
        for (int i = 0; i < 4; ++i) {
            const int c = m0 + ty * 4 + i;
            const long nidx = n0 + tx * 4;
            const float4 xv = *(const float4*)(X + ((long)b * 256 + c) * 4096 + nidx);
            const float4 wv = *(const float4*)(WP + ((long)b * 16 + (c >> 4)) * 4096 + nidx);
            float4 o;
            o.x = xv.x * sigmoidf_(wv.x) + acc[i][0];
            o.y = xv.y * sigmoidf_(wv.y) + acc[i][1];
            o.z = xv.z * sigmoidf_(wv.z) + acc[i][2];
            o.w = xv.w * sigmoidf_(wv.w) + acc[i][3];
            *(float4*)(Cb + (long)c * N + nidx) = o;
        }
    } else {
        #pragma unroll
        for (int i = 0; i < 4; ++i) {
            const float4 o = make_float4(acc[i][0], acc[i][1], acc[i][2], acc[i][3]);
            *(float4*)(Cb + (long)(m0 + ty * 4 + i) * N + n0 + tx * 4) = o;
        }
    }
}

// ---------------------------------------------------------------------------
// Per-(b,h) attention in Gram space (fallback path only).
// ---------------------------------------------------------------------------
__global__ __launch_bounds__(256) void attn_kernel(
    const float* __restrict__ T, const float* __restrict__ wqkv,
    const float* __restrict__ temp, float* __restrict__ Mout, long tStride)
{
    const int bh = blockIdx.x;
    const int b = bh >> 3, h = bh & 7;
    const int t = threadIdx.x;
    __shared__ float Tq[32][260];
    __shared__ float qk[32][33];
    __shared__ float qn[32], kn[32];
    const float* Tb = T + (long)b * tStride;

    for (int f = t; f < 32 * 64; f += 256) {
        const int r = f >> 6, c4 = f & 63;
        *(float4*)&Tq[r][c4 * 4] = *(const float4*)(Tb + (long)(h * 32 + r) * 256 + c4 * 4);
    }
    __syncthreads();

    if (t < 32) {
        float s = 0.f;
        const float* wq = wqkv + (long)(h * 32 + t) * 256;
        #pragma unroll 4
        for (int k = 0; k < 256; k += 4) {
            const float4 a = *(const float4*)&Tq[t][k];
            const float4 w = *(const float4*)(wq + k);
            s += a.x * w.x + a.y * w.y + a.z * w.z + a.w * w.w;
        }
        qn[t] = fmaxf(sqrtf(s), 1e-12f);
    } else if (t < 64) {
        const int d = t - 32;
        float s = 0.f;
        const float* tk = Tb + (long)(256 + h * 32 + d) * 256;
        const float* wk = wqkv + (long)(256 + h * 32 + d) * 256;
        #pragma unroll 4
        for (int k = 0; k < 256; k += 4) {
            const float4 a = *(const float4*)(tk + k);
            const float4 w = *(const float4*)(wk + k);
            s += a.x * w.x + a.y * w.y + a.z * w.z + a.w * w.w;
        }
        kn[d] = fmaxf(sqrtf(s), 1e-12f);
    }

    {
        const int c = t >> 3, d0 = (t & 7) * 4;
        float s0 = 0, s1 = 0, s2 = 0, s3 = 0;
        const float* wk0 = wqkv + (long)(256 + h * 32 + d0) * 256;
        #pragma unroll 4
        for (int k = 0; k < 256; k += 4) {
            const float4 a = *(const float4*)&Tq[c][k];
            const float4 w0 = *(const float4*)(wk0 + k);
            const float4 w1 = *(const float4*)(wk0 + 256 + k);
            const float4 w2 = *(const float4*)(wk0 + 512 + k);
            const float4 w3 = *(const float4*)(wk0 + 768 + k);
            s0 += a.x * w0.x + a.y * w0.y + a.z * w0.z + a.w * w0.w;
            s1 += a.x * w1.x + a.y * w1.y + a.z * w1.z + a.w * w1.w;
            s2 += a.x * w2.x + a.y * w2.y + a.z * w2.z + a.w * w2.w;
            s3 += a.x * w3.x + a.y * w3.y + a.z * w3.z + a.w * w3.w;
        }
        qk[c][d0 + 0] = s0;
        qk[c][d0 + 1] = s1;
        qk[c][d0 + 2] = s2;
        qk[c][d0 + 3] = s3;
    }
    __syncthreads();

    if (t < 32) {
        const float tscale = temp[h];
        const float qin = tscale / qn[t];
        float lg[32];
        float mx = -1e30f;
        #pragma unroll
        for (int d = 0; d < 32; ++d) {
            const float l = qk[t][d] * qin / kn[d];
            lg[d] = l;
            mx = fmaxf(mx, l);
        }
        float s = 0.f;
        #pragma unroll
        for (int d = 0; d < 32; ++d) { lg[d] = __expf(lg[d] - mx); s += lg[d]; }
        const float inv = 1.0f / s;
        #pragma unroll
        for (int d = 0; d < 32; ++d) qk[t][d] = lg[d] * inv;
    }
    __syncthreads();

    float accm[32];
    #pragma unroll
    for (int c = 0; c < 32; ++c) accm[c] = 0.f;
    const float* wvp = wqkv + (long)(512 + h * 32) * 256 + t;
    #pragma unroll 4
    for (int d = 0; d < 32; ++d) {
        const float wvv = wvp[(long)d * 256];
        #pragma unroll
        for (int c = 0; c < 32; ++c) accm[c] += qk[c][d] * wvv;
    }
    float* mo = Mout + (long)b * 256 * 256 + (long)(h * 32) * 256 + t;
    #pragma unroll
    for (int c = 0; c < 32; ++c) mo[(long)c * 256] = accm[c];
}

// ---------------------------------------------------------------------------
// W2[b][g][i] = (softmax(gn_b) . P[b][16g:16g+16][i])   (output type templated)
// ---------------------------------------------------------------------------
template <typename OT>
__global__ __launch_bounds__(256) void w2_kernel(
    const float* __restrict__ P, const float* __restrict__ gnb, OT* __restrict__ W2)
{
    const int b = blockIdx.x, i = threadIdx.x;
    float e[16];
    float mx = -1e30f;
    #pragma unroll
    for (int c = 0; c < 16; ++c) mx = fmaxf(mx, gnb[c]);
    float s = 0.f;
    #pragma unroll
    for (int c = 0; c < 16; ++c) { e[c] = __expf(gnb[c] - mx); s += e[c]; }
    const float inv = 1.0f / s;
    const float* Pb = P + (long)b * 256 * 256 + i;
    #pragma unroll
    for (int g = 0; g < 16; ++g) {
        float acc = 0.f;
        #pragma unroll
        for (int c = 0; c < 16; ++c) acc += e[c] * Pb[(long)(g * 16 + c) * 256];
        W2[((long)b * 16 + g) * 256 + i] = (OT)(acc * inv);
    }
}

// ---------------------------------------------------------------------------
// WP[b][g][n] = W2_b[g] . X_b[:,n]  (fallback path only)
// ---------------------------------------------------------------------------
__global__ __launch_bounds__(256) void wpre_kernel(
    const float* __restrict__ W2, const float* __restrict__ X, float* __restrict__ WP)
{
    __shared__ float w2s[16][260];
    const int b = blockIdx.y;
    const int n = blockIdx.x * 256 + threadIdx.x;
    for (int f = threadIdx.x; f < 16 * 64; f += 256) {
        const int g = f >> 6, c4 = f & 63;
        *(float4*)&w2s[g][c4 * 4] = *(const float4*)(W2 + ((long)b * 16 + g) * 256 + c4 * 4);
    }
    __syncthreads();
    float acc[16] = {};
    const float* xb = X + (long)b * 256 * 4096 + n;
    for (int k = 0; k < 256; ++k) {
        const float xv = xb[(long)k * 4096];
        #pragma unroll
        for (int g = 0; g < 16; ++g) acc[g] += w2s[g][k] * xv;
    }
    #pragma unroll
    for (int g = 0; g < 16; ++g) WP[((long)b * 16 + g) * 4096 + n] = acc[g];
}

// ---------------------------------------------------------------------------
extern "C" void kernel_launch(void* const* d_in, const int* in_sizes, int n_in,
                              void* d_out, int out_size, void* d_ws, size_t ws_size,
                              hipStream_t stream)
{
    const float* x     = (const float*)d_in[0];
    const float* gnb   = (const float*)d_in[4];
    const float* wqkv  = (const float*)d_in[5];
    const float* wproj = (const float*)d_in[6];
    const float* temp  = (const float*)d_in[7];
    float* out = (float*)d_out;

    if (ws_size >= 82051072ULL) {
        // Workspace: [Xh 32M][Xt 32M][G/S1/Mm 4M][pool: T(8M)+Qn(32K) -> {P,Ph,W2h}]
        // Gram split-K partials (32 MB) live in d_out (dead until out_fused).
        char* w = (char*)d_ws;
        _Float16* Xh = (_Float16*)w;
        _Float16* Xt = (_Float16*)(w + 33554432);
        float*    G  = (float*)(w + 67108864);
        float*    S1 = G;                           // overlay: G dead after T-gemm
        float*    Mm = G;                           // overlay: attn2 stages S1 in LDS
        char*     pool = w + 71303168;
        float*    T  = (float*)pool;                // 512x256x16 fp32 = 8MB
        float*    Qn = (float*)(pool + 8388608);    // 32KB norms^2
        float*    P  = (float*)pool;                // overwrites dead T
        _Float16* Ph = (_Float16*)(pool + 4194304);
        _Float16* W2h = (_Float16*)(pool + 4194304 + 2097152);
        float*    pG = (float*)d_out;               // scratch: fully overwritten later

        // 1. X -> Xh + Xt (one pass)
        prep_fused<<<dim3(64, 4, 16), 256, 0, stream>>>(x, Xh, Xt);
        // 2. Gram split-K partials into d_out
        gram_split<<<dim3(2, 2, 128), 256, 0, stream>>>(Xh, pG);
        // 3. G = sum of 8 partials
        reduce_g<<<1024, 256, 0, stream>>>(pG, G);
        // 4. T = w_qkv[0:512] @ G_b
        gemm64<false, false><<<dim3(4, 8, 16), 256, 0, stream>>>(
            wqkv, G, T, 512, 256, 256, 0L, 65536L, 131072L, nullptr, nullptr);
        // 5. Qn[b][r] = T[b][r].wqkv[r]
        snorm_kernel<<<2048, 256, 0, stream>>>(T, wqkv, Qn);
        // 6. S1 = Tq @ Wk^T (overlays dead G)
        gemm64<true, false><<<dim3(4, 4, 16), 256, 0, stream>>>(
            T, wqkv + 65536, S1, 256, 256, 256, 131072L, 0L, 65536L, nullptr, nullptr);
        // 7. softmax + @Wv -> Mm (aliases S1, LDS-staged)
        attn2_kernel<<<128, 256, 0, stream>>>(S1, Qn, wqkv, temp, Mm);
        // 8. P_b = w_proj @ Mm_b (overwrites dead T)
        gemm64<false, false><<<dim3(4, 4, 16), 256, 0, stream>>>(
            wproj, Mm, P, 256, 256, 256, 0L, 65536L, 65536L, nullptr, nullptr);
        // 9. P -> f16
        cvt_half<<<1024, 256, 0, stream>>>(P, Ph);
        // 10. W2h = softmax(gn_b)-weighted group sums of P rows (f16)
        w2_kernel<_Float16><<<16, 256, 0, stream>>>(P, gnb, W2h);
        // 11. out = Ph@X + Xh*sigmoid(W2h@X)  (fused, vectorized epilogue)
        out_fused<<<dim3(32, 2, 16), 256, 0, stream>>>(Ph, Xt, Xh, W2h, out);
    } else {
        // Fallback: fp32 path (~30 MB workspace)
        float* ws = (float*)d_ws;
        float* G  = ws;
        float* T  = G  + 16L * 65536;
        float* Mm = T  + 16L * 196608;
        float* P  = Mm + 16L * 65536;
        float* W2 = P  + 16L * 65536;
        float* WP = W2 + 16L * 4096;

        gemm64<true, false><<<dim3(4, 4, 16), 256, 0, stream>>>(
            x, x, G, 256, 256, 4096, 1048576L, 1048576L, 65536L, nullptr, nullptr);
        gemm64<false, false><<<dim3(4, 12, 16), 256, 0, stream>>>(
            wqkv, G, T, 768, 256, 256, 0L, 65536L, 196608L, nullptr, nullptr);
        attn_kernel<<<128, 256, 0, stream>>>(T, wqkv, temp, Mm, 196608L);
        gemm64<false, false><<<dim3(4, 4, 16), 256, 0, stream>>>(
            wproj, Mm, P, 256, 256, 256, 0L, 65536L, 65536L, nullptr, nullptr);
        w2_kernel<float><<<16, 256, 0, stream>>>(P, gnb, W2);
        wpre_kernel<<<dim3(16, 16), 256, 0, stream>>>(W2, x, WP);
        gemm64<false, true><<<dim3(64, 4, 16), 256, 0, stream>>>(
            P, x, out, 256, 4096, 256, 65536L, 1048576L, 1048576L, x, WP);
    }
}

// Round 7
// 158.645 us; speedup vs baseline: 2.8449x; 1.0005x over previous
//
#include <hip/hip_runtime.h>
#include <math.h>

// Problem constants: B=16, C=256, H=W=64, N=4096, GROUPS=16 (cg=16), HEADS=8 (ch=32)

__device__ __forceinline__ float sigmoidf_(float v) { return 1.0f / (1.0f + __expf(-v)); }

typedef _Float16 half8 __attribute__((ext_vector_type(8)));
typedef _Float16 half4 __attribute__((ext_vector_type(4)));
typedef float f32x4 __attribute__((ext_vector_type(4)));

#define GLOAD_LDS16(gp, lp)                                                     \
    __builtin_amdgcn_global_load_lds(                                           \
        (const __attribute__((address_space(1))) void*)(gp),                    \
        (__attribute__((address_space(3))) void*)(lp), 16, 0, 0)

// ---------------------------------------------------------------------------
// prep_fused: X (fp32 [b][256][4096]) -> Xh (f16 row-major) + Xt (f16 [b][4096][256])
// ---------------------------------------------------------------------------
__global__ __launch_bounds__(256) void prep_fused(
    const float* __restrict__ X, _Float16* __restrict__ Xh, _Float16* __restrict__ Xt)
{
    __shared__ float tl[64][68];
    const int b = blockIdx.z, c0 = blockIdx.y * 64, n0 = blockIdx.x * 64;
    const int t = threadIdx.x;
    const int r0 = t >> 4;
    const int q = (t & 15) * 4;
    const float* Xb = X + ((long)b * 256 + c0) * 4096 + n0;
    _Float16* Xhb = Xh + ((long)b * 256 + c0) * 4096 + n0;
    #pragma unroll
    for (int i = 0; i < 4; ++i) {
        const int r = r0 + i * 16;
        const float4 v = *(const float4*)(Xb + (long)r * 4096 + q);
        tl[r][q + 0] = v.x; tl[r][q + 1] = v.y;
        tl[r][q + 2] = v.z; tl[r][q + 3] = v.w;
        half4 h = { (_Float16)v.x, (_Float16)v.y, (_Float16)v.z, (_Float16)v.w };
        *(half4*)(Xhb + (long)r * 4096 + q) = h;
    }
    __syncthreads();
    const int nn = t >> 2, cc = (t & 3) * 16;
    _Float16* Xtb = Xt + ((long)b * 4096 + n0 + nn) * 256 + c0 + cc;
    half8 o0, o1;
    #pragma unroll
    for (int k = 0; k < 8; ++k) o0[k] = (_Float16)tl[cc + k][nn];
    #pragma unroll
    for (int k = 0; k < 8; ++k) o1[k] = (_Float16)tl[cc + 8 + k][nn];
    *(half8*)(Xtb) = o0;
    *(half8*)(Xtb + 8) = o1;
}

// ---------------------------------------------------------------------------
// Gram split-K: pG[s][b] = Xh_b[:, s*512:(s+1)*512] . (same)^T
// pG lives in d_out (dead until out_fused overwrites). Slab stride 1048576 fl.
// ---------------------------------------------------------------------------
__global__ __launch_bounds__(256) void gram_split(const _Float16* __restrict__ Xh,
                                                  float* __restrict__ pG)
{
    __shared__ _Float16 Al[128 * 32];
    __shared__ _Float16 Bl[128 * 32];
    const int z = blockIdx.z, b = z >> 3, s = z & 7;
    const int m0 = blockIdx.y * 128, n0 = blockIdx.x * 128;
    const _Float16* Xb = Xh + (long)b * 256 * 4096;
    const int t = threadIdx.x, lane = t & 63, wv = t >> 6;
    const int wm = (wv >> 1) * 64, wn = (wv & 1) * 64;
    f32x4 acc[4][4] = {};

    const int kbeg = s * 512, kend = kbeg + 512;
    for (int k0 = kbeg; k0 < kend; k0 += 32) {
        __syncthreads();
        #pragma unroll
        for (int r = 0; r < 2; ++r) {
            const int e = (r * 256 + t) * 8;
            const int row = e >> 5, col = e & 31;
            GLOAD_LDS16(Xb + (long)(m0 + row) * 4096 + k0 + col, &Al[e]);
            GLOAD_LDS16(Xb + (long)(n0 + row) * 4096 + k0 + col, &Bl[e]);
        }
        __syncthreads();
        half8 af[4], bf[4];
        #pragma unroll
        for (int f = 0; f < 4; ++f) {
            af[f] = *(const half8*)&Al[(wm + f * 16 + (lane & 15)) * 32 + (lane >> 4) * 8];
            bf[f] = *(const half8*)&Bl[(wn + f * 16 + (lane & 15)) * 32 + (lane >> 4) * 8];
        }
        #pragma unroll
        for (int i = 0; i < 4; ++i)
            #pragma unroll
            for (int j = 0; j < 4; ++j)
                acc[i][j] = __builtin_amdgcn_mfma_f32_16x16x32_f16(af[i], bf[j], acc[i][j], 0, 0, 0);
    }
    float* pGb = pG + (long)s * 1048576 + (long)b * 65536;
    #pragma unroll
    for (int i = 0; i < 4; ++i)
        #pragma unroll
        for (int j = 0; j < 4; ++j) {
            const int row = m0 + wm + i * 16 + (lane >> 4) * 4;
            const int col = n0 + wn + j * 16 + (lane & 15);
            float* gp = pGb + (long)row * 256 + col;
            #pragma unroll
            for (int r = 0; r < 4; ++r) gp[(long)r * 256] = acc[i][j][r];
        }
}

// ---------------------------------------------------------------------------
// gemm_t8: T[b] = wqkv[0:512] @ (sum_s pG[s][b])  -- 8-slab reduce fused into
// B-staging (fixed order -> identical to reduce-then-gemm). M=512,N=256,K=256.
// ---------------------------------------------------------------------------
__global__ __launch_bounds__(256) void gemm_t8(
    const float* __restrict__ A, const float* __restrict__ pG, float* __restrict__ T)
{
    __shared__ float As[32][68];
    __shared__ float Bs[32][68];
    const int b = blockIdx.z;
    const float* Bb = pG + (long)b * 65536;
    float* Cb = T + (long)b * 131072;
    const int t = threadIdx.x;
    const int tx = t & 15, ty = t >> 4;
    const int m0 = blockIdx.y * 64, n0 = blockIdx.x * 64;

    float acc[4][4] = {};

    for (int k0 = 0; k0 < 256; k0 += 32) {
        __syncthreads();
        #pragma unroll
        for (int f0 = 0; f0 < 512; f0 += 256) {
            const int f = f0 + t;
            const int row = f >> 3, c4 = f & 7;
            const float4 v = *(const float4*)(A + (long)(m0 + row) * 256 + k0 + c4 * 4);
            As[c4 * 4 + 0][row] = v.x;
            As[c4 * 4 + 1][row] = v.y;
            As[c4 * 4 + 2][row] = v.z;
            As[c4 * 4 + 3][row] = v.w;
        }
        #pragma unroll
        for (int f0 = 0; f0 < 512; f0 += 256) {
            const int f = f0 + t;
            const int kk = f >> 4, c4 = f & 15;
            const float* bp = Bb + (long)(k0 + kk) * 256 + n0 + c4 * 4;
            f32x4 sum = {};
            #pragma unroll
            for (int s = 0; s < 8; ++s) {
                const float4 v = *(const float4*)(bp + (long)s * 1048576);
                sum[0] += v.x; sum[1] += v.y; sum[2] += v.z; sum[3] += v.w;
            }
            *(f32x4*)&Bs[kk][c4 * 4] = sum;
        }
        __syncthreads();
        #pragma unroll
        for (int kk = 0; kk < 32; ++kk) {
            const float4 av = *(const float4*)&As[kk][ty * 4];
            const float4 bv = *(const float4*)&Bs[kk][tx * 4];
            const float a0 = av.x, a1 = av.y, a2 = av.z, a3 = av.w;
            const float b0 = bv.x, b1 = bv.y, b2 = bv.z, b3 = bv.w;
            acc[0][0] += a0 * b0; acc[0][1] += a0 * b1; acc[0][2] += a0 * b2; acc[0][3] += a0 * b3;
            acc[1][0] += a1 * b0; acc[1][1] += a1 * b1; acc[1][2] += a1 * b2; acc[1][3] += a1 * b3;
            acc[2][0] += a2 * b0; acc[2][1] += a2 * b1; acc[2][2] += a2 * b2; acc[2][3] += a2 * b3;
            acc[3][0] += a3 * b0; acc[3][1] += a3 * b1; acc[3][2] += a3 * b2; acc[3][3] += a3 * b3;
        }
    }
    #pragma unroll
    for (int i = 0; i < 4; ++i) {
        const float4 o = make_float4(acc[i][0], acc[i][1], acc[i][2], acc[i][3]);
        *(float4*)(Cb + (long)(m0 + ty * 4 + i) * 256 + n0 + tx * 4) = o;
    }
}

// ---------------------------------------------------------------------------
// snorm: Qn[b][r] = T[b][r] . wqkv[r]  for r in [0,512)  (q/k norms^2).
// ---------------------------------------------------------------------------
__global__ __launch_bounds__(256) void snorm_kernel(
    const float* __restrict__ T, const float* __restrict__ wqkv,
    float* __restrict__ Qn)
{
    const int gw = (int)((blockIdx.x * 256 + threadIdx.x) >> 6);
    const int lane = threadIdx.x & 63;
    const int b = gw >> 9, r = gw & 511;
    const float4 a = *(const float4*)(T + (long)b * 131072 + (long)r * 256 + lane * 4);
    const float4 w = *(const float4*)(wqkv + (long)r * 256 + lane * 4);
    float s = a.x * w.x + a.y * w.y + a.z * w.z + a.w * w.w;
    #pragma unroll
    for (int off = 32; off; off >>= 1) s += __shfl_xor(s, off, 64);
    if (lane == 0) Qn[(long)b * 512 + r] = s;
}

// ---------------------------------------------------------------------------
// attn2: per (b,h): softmax(S1 head-block / (qn kn) * temp) @ Wv_h -> M rows.
// S1 and Mout alias (tile staged to LDS first; blocks touch disjoint rows).
// ---------------------------------------------------------------------------
__global__ __launch_bounds__(256) void attn2_kernel(
    const float* __restrict__ S1, const float* __restrict__ Qn,
    const float* __restrict__ wqkv, const float* __restrict__ temp,
    float* __restrict__ Mout)
{
    const int bh = blockIdx.x;
    const int b = bh >> 3, h = bh & 7;
    const int t = threadIdx.x;
    __shared__ float pa[32][36];
    __shared__ float qn[32], kn[32];

    {
        const int r = t >> 3, c4 = (t & 7) * 4;
        const float4 v = *(const float4*)(
            S1 + (long)b * 65536 + (long)(h * 32 + r) * 256 + h * 32 + c4);
        pa[r][c4 + 0] = v.x; pa[r][c4 + 1] = v.y;
        pa[r][c4 + 2] = v.z; pa[r][c4 + 3] = v.w;
    }
    if (t < 32)
        qn[t] = fmaxf(sqrtf(Qn[(long)b * 512 + h * 32 + t]), 1e-12f);
    else if (t < 64)
        kn[t - 32] = fmaxf(sqrtf(Qn[(long)b * 512 + 256 + h * 32 + (t - 32)]), 1e-12f);
    __syncthreads();

    if (t < 32) {
        const float qin = temp[h] / qn[t];
        float lg[32];
        float mx = -1e30f;
        #pragma unroll
        for (int d = 0; d < 32; ++d) {
            const float l = pa[t][d] * qin / kn[d];
            lg[d] = l;
            mx = fmaxf(mx, l);
        }
        float s = 0.f;
        #pragma unroll
        for (int d = 0; d < 32; ++d) { lg[d] = __expf(lg[d] - mx); s += lg[d]; }
        const float inv = 1.0f / s;
        #pragma unroll
        for (int d = 0; d < 32; ++d) pa[t][d] = lg[d] * inv;
    }
    __syncthreads();

    float accm[32];
    #pragma unroll
    for (int c = 0; c < 32; ++c) accm[c] = 0.f;
    const float* wvp = wqkv + (long)(512 + h * 32) * 256 + t;
    #pragma unroll 4
    for (int d = 0; d < 32; ++d) {
        const float wvv = wvp[(long)d * 256];
        #pragma unroll
        for (int c = 0; c < 32; ++c) accm[c] += pa[c][d] * wvv;
    }
    float* mo = Mout + (long)b * 65536 + (long)(h * 32) * 256 + t;
    #pragma unroll
    for (int c = 0; c < 32; ++c) mo[(long)c * 256] = accm[c];
}

// ---------------------------------------------------------------------------
// out_fused: out_b = Ph_b @ X_b (via Xt) + Xh*sigmoid(W2h@X), with a 2-phase
// double-buffered K-loop (stage k+1 overlaps MFMA of k; ONE barrier/step whose
// implicit vmcnt(0) drain is the counted wait) and LDS-staged f4 epilogue.
// ---------------------------------------------------------------------------
__global__ __launch_bounds__(256) void out_fused(
    const _Float16* __restrict__ Ph, const _Float16* __restrict__ Xt,
    const _Float16* __restrict__ Xh, const _Float16* __restrict__ W2h,
    float* __restrict__ out)
{
    __shared__ __align__(16) char smem[64 * 132 * 4];   // 33792B: [buf0 16K][buf1 16K]
    __shared__ float S2l[16][132];
    float (*cst)[132] = (float(*)[132])smem;

    const int b = blockIdx.z;
    const int m0 = blockIdx.y * 128, n0 = blockIdx.x * 128;
    const _Float16* Ab = Ph + (long)b * 65536;
    const _Float16* Bb = Xt + (long)b * 1048576;
    const _Float16* W2b = W2h + (long)b * 4096;
    const int t = threadIdx.x, lane = t & 63, wv = t >> 6;
    const int wm = (wv >> 1) * 64, wn = (wv & 1) * 64;

    f32x4 acc[4][4] = {};
    f32x4 s2acc[4] = {};

#define OF_STAGE(P, K0) do {                                                     \
        _Float16* Al_ = (_Float16*)(smem + (P) * 16384);                         \
        _Float16* Bl_ = (_Float16*)(smem + (P) * 16384 + 8192);                  \
        _Pragma("unroll")                                                        \
        for (int r_ = 0; r_ < 2; ++r_) {                                         \
            const int e_ = (r_ * 256 + t) * 8;                                   \
            const int row_ = e_ >> 5, col_ = e_ & 31;                            \
            GLOAD_LDS16(Ab + (long)(m0 + row_) * 256 + (K0) + col_, &Al_[e_]);   \
            GLOAD_LDS16(Bb + (long)(n0 + row_) * 256 + (K0) + col_, &Bl_[e_]);   \
        } } while (0)

    OF_STAGE(0, 0);
    __syncthreads();                    // first tile landed (vmcnt(0) drain)
    int cur = 0;
    for (int ks = 0; ks < 8; ++ks) {
        if (ks < 7) OF_STAGE(cur ^ 1, (ks + 1) * 32);   // overlap with MFMA below
        const int k0 = ks * 32;
        const half8 wf = *(const half8*)(W2b + (long)(lane & 15) * 256 + k0 + (lane >> 4) * 8);
        const _Float16* Al = (const _Float16*)(smem + cur * 16384);
        const _Float16* Bl = (const _Float16*)(smem + cur * 16384 + 8192);
        half8 af[4], bf[4];
        #pragma unroll
        for (int f = 0; f < 4; ++f) {
            af[f] = *(const half8*)&Al[(wm + f * 16 + (lane & 15)) * 32 + (lane >> 4) * 8];
            bf[f] = *(const half8*)&Bl[(wn + f * 16 + (lane & 15)) * 32 + (lane >> 4) * 8];
        }
        #pragma unroll
        for (int i = 0; i < 4; ++i)
            #pragma unroll
            for (int j = 0; j < 4; ++j)
                acc[i][j] = __builtin_amdgcn_mfma_f32_16x16x32_f16(af[i], bf[j], acc[i][j], 0, 0, 0);
        #pragma unroll
        for (int j = 0; j < 4; ++j)
            s2acc[j] = __builtin_amdgcn_mfma_f32_16x16x32_f16(wf, bf[j], s2acc[j], 0, 0, 0);
        __syncthreads();                // drains vmcnt(0): next tile landed
        cur ^= 1;
    }
#undef OF_STAGE

    // smem free (all reads done at final barrier); becomes cst
    if (wm == 0) {
        #pragma unroll
        for (int j = 0; j < 4; ++j)
            #pragma unroll
            for (int r = 0; r < 4; ++r)
                S2l[(lane >> 4) * 4 + r][wn + j * 16 + (lane & 15)] = s2acc[j][r];
    }

    const _Float16* Xhb = Xh + (long)b * 1048576;
    float* ob = out + (long)b * 1048576;

    #pragma unroll
    for (int hf = 0; hf < 2; ++hf) {
        if (wm == hf * 64) {
            #pragma unroll
            for (int i = 0; i < 4; ++i)
                #pragma unroll
                for (int j = 0; j < 4; ++j)
                    #pragma unroll
                    for (int r = 0; r < 4; ++r)
                        cst[i * 16 + (lane >> 4) * 4 + r][wn + j * 16 + (lane & 15)] = acc[i][j][r];
        }
        __syncthreads();
        #pragma unroll
        for (int it = 0; it < 8; ++it) {
            const int row = it * 8 + (t >> 5);
            const int col = (t & 31) * 4;
            const int c = m0 + hf * 64 + row;
            const float4 v = *(const float4*)&cst[row][col];
            const float4 s2 = *(const float4*)&S2l[c >> 4][col];
            const half4 xv = *(const half4*)(Xhb + (long)c * 4096 + n0 + col);
            float4 o;
            o.x = (float)xv[0] * sigmoidf_(s2.x) + v.x;
            o.y = (float)xv[1] * sigmoidf_(s2.y) + v.y;
            o.z = (float)xv[2] * sigmoidf_(s2.z) + v.z;
            o.w = (float)xv[3] * sigmoidf_(s2.w) + v.w;
            *(float4*)(ob + (long)c * 4096 + n0 + col) = o;
        }
        __syncthreads();
    }
}

// ---------------------------------------------------------------------------
// Generic 64x64-tile fp32 GEMM. DIAG: n0=m0 (block-diagonal tiles only).
// HC: also write an f16 copy of C (same layout).
// ---------------------------------------------------------------------------
template <bool BT, bool EPI, bool DIAG, bool HC>
__global__ __launch_bounds__(256) void gemm64(
    const float* __restrict__ A, const float* __restrict__ B, float* __restrict__ C,
    int M, int N, int K, long sA, long sB, long sC,
    const float* __restrict__ X, const float* __restrict__ WP,
    _Float16* __restrict__ Hc)
{
    __shared__ float As[32][68];
    __shared__ float Bs[32][68];
    const int b = blockIdx.z;
    const float* Ab = A + (long)b * sA;
    const float* Bb = B + (long)b * sB;
    float* Cb = C + (long)b * sC;
    const int t = threadIdx.x;
    const int tx = t & 15, ty = t >> 4;
    const int m0 = blockIdx.y * 64;
    const int n0 = DIAG ? m0 : blockIdx.x * 64;

    float acc[4][4] = {};

    for (int k0 = 0; k0 < K; k0 += 32) {
        __syncthreads();
        #pragma unroll
        for (int f0 = 0; f0 < 512; f0 += 256) {
            const int f = f0 + t;
            const int row = f >> 3, c4 = f & 7;
            const float4 v = *(const float4*)(Ab + (long)(m0 + row) * K + k0 + c4 * 4);
            As[c4 * 4 + 0][row] = v.x;
            As[c4 * 4 + 1][row] = v.y;
            As[c4 * 4 + 2][row] = v.z;
            As[c4 * 4 + 3][row] = v.w;
        }
        if (BT) {
            #pragma unroll
            for (int f0 = 0; f0 < 512; f0 += 256) {
                const int f = f0 + t;
                const int row = f >> 3, c4 = f & 7;
                const float4 v = *(const float4*)(Bb + (long)(n0 + row) * K + k0 + c4 * 4);
                Bs[c4 * 4 + 0][row] = v.x;
                Bs[c4 * 4 + 1][row] = v.y;
                Bs[c4 * 4 + 2][row] = v.z;
                Bs[c4 * 4 + 3][row] = v.w;
            }
        } else {
            #pragma unroll
            for (int f0 = 0; f0 < 512; f0 += 256) {
                const int f = f0 + t;
                const int kk = f >> 4, c4 = f & 15;
                *(float4*)&Bs[kk][c4 * 4] =
                    *(const float4*)(Bb + (long)(k0 + kk) * N + n0 + c4 * 4);
            }
        }
        __syncthreads();
        #pragma unroll
        for (int kk = 0; kk < 32; ++kk) {
            const float4 av = *(const float4*)&As[kk][ty * 4];
            const float4 bv = *(const float4*)&Bs[kk][tx * 4];
            const float a0 = av.x, a1 = av.y, a2 = av.z, a3 = av.w;
            const float b0 = bv.x, b1 = bv.y, b2 = bv.z, b3 = bv.w;
            acc[0][0] += a0 * b0; acc[0][1] += a0 * b1; acc[0][2] += a0 * b2; acc[0][3] += a0 * b3;
            acc[1][0] += a1 * b0; acc[1][1] += a1 * b1; acc[1][2] += a1 * b2; acc[1][3] += a1 * b3;
            acc[2][0] += a2 * b0; acc[2][1] += a2 * b1; acc[2][2] += a2 * b2; acc[2][3] += a2 * b3;
            acc[3][0] += a3 * b0; acc[3][1] += a3 * b1; acc[3][2] += a3 * b2; acc[3][3] += a3 * b3;
        }
    }

    if (EPI) {
        #pragma unroll
        for (int i = 0; i < 4; ++i) {
            const int c = m0 + ty * 4 + i;
            const long nidx = n0 + tx * 4;
            const float4 xv = *(const float4*)(X + ((long)b * 256 + c) * 4096 + nidx);
            const float4 wv = *(const float4*)(WP + ((long)b * 16 + (c >> 4)) * 4096 + nidx);
            float4 o;
            o.x = xv.x * sigmoidf_(wv.x) + acc[i][0];
            o.y = xv.y * sigmoidf_(wv.y) + acc[i][1];
            o.z = xv.z * sigmoidf_(wv.z) + acc[i][2];
            o.w = xv.w * sigmoidf_(wv.w) + acc[i][3];
            *(float4*)(Cb + (long)c * N + nidx) = o;
        }
    } else {
        #pragma unroll
        for (int i = 0; i < 4; ++i) {
            const float4 o = make_float4(acc[i][0], acc[i][1], acc[i][2], acc[i][3]);
            *(float4*)(Cb + (long)(m0 + ty * 4 + i) * N + n0 + tx * 4) = o;
            if (HC) {
                half4 h = { (_Float16)o.x, (_Float16)o.y, (_Float16)o.z, (_Float16)o.w };
                *(half4*)(Hc + (long)b * sC + (long)(m0 + ty * 4 + i) * N + n0 + tx * 4) = h;
            }
        }
    }
}

// ---------------------------------------------------------------------------
// Per-(b,h) attention in Gram space (fallback path only).
// ---------------------------------------------------------------------------
__global__ __launch_bounds__(256) void attn_kernel(
    const float* __restrict__ T, const float* __restrict__ wqkv,
    const float* __restrict__ temp, float* __restrict__ Mout, long tStride)
{
    const int bh = blockIdx.x;
    const int b = bh >> 3, h = bh & 7;
    const int t = threadIdx.x;
    __shared__ float Tq[32][260];
    __shared__ float qk[32][33];
    __shared__ float qn[32], kn[32];
    const float* Tb = T + (long)b * tStride;

    for (int f = t; f < 32 * 64; f += 256) {
        const int r = f >> 6, c4 = f & 63;
        *(float4*)&Tq[r][c4 * 4] = *(const float4*)(Tb + (long)(h * 32 + r) * 256 + c4 * 4);
    }
    __syncthreads();

    if (t < 32) {
        float s = 0.f;
        const float* wq = wqkv + (long)(h * 32 + t) * 256;
        #pragma unroll 4
        for (int k = 0; k < 256; k += 4) {
            const float4 a = *(const float4*)&Tq[t][k];
            const float4 w = *(const float4*)(wq + k);
            s += a.x * w.x + a.y * w.y + a.z * w.z + a.w * w.w;
        }
        qn[t] = fmaxf(sqrtf(s), 1e-12f);
    } else if (t < 64) {
        const int d = t - 32;
        float s = 0.f;
        const float* tk = Tb + (long)(256 + h * 32 + d) * 256;
        const float* wk = wqkv + (long)(256 + h * 32 + d) * 256;
        #pragma unroll 4
        for (int k = 0; k < 256; k += 4) {
            const float4 a = *(const float4*)(tk + k);
            const float4 w = *(const float4*)(wk + k);
            s += a.x * w.x + a.y * w.y + a.z * w.z + a.w * w.w;
        }
        kn[d] = fmaxf(sqrtf(s), 1e-12f);
    }

    {
        const int c = t >> 3, d0 = (t & 7) * 4;
        float s0 = 0, s1 = 0, s2 = 0, s3 = 0;
        const float* wk0 = wqkv + (long)(256 + h * 32 + d0) * 256;
        #pragma unroll 4
        for (int k = 0; k < 256; k += 4) {
            const float4 a = *(const float4*)&Tq[c][k];
            const float4 w0 = *(const float4*)(wk0 + k);
            const float4 w1 = *(const float4*)(wk0 + 256 + k);
            const float4 w2 = *(const float4*)(wk0 + 512 + k);
            const float4 w3 = *(const float4*)(wk0 + 768 + k);
            s0 += a.x * w0.x + a.y * w0.y + a.z * w0.z + a.w * w0.w;
            s1 += a.x * w1.x + a.y * w1.y + a.z * w1.z + a.w * w1.w;
            s2 += a.x * w2.x + a.y * w2.y + a.z * w2.z + a.w * w2.w;
            s3 += a.x * w3.x + a.y * w3.y + a.z * w3.z + a.w * w3.w;
        }
        qk[c][d0 + 0] = s0;
        qk[c][d0 + 1] = s1;
        qk[c][d0 + 2] = s2;
        qk[c][d0 + 3] = s3;
    }
    __syncthreads();

    if (t < 32) {
        const float tscale = temp[h];
        const float qin = tscale / qn[t];
        float lg[32];
        float mx = -1e30f;
        #pragma unroll
        for (int d = 0; d < 32; ++d) {
            const float l = qk[t][d] * qin / kn[d];
            lg[d] = l;
            mx = fmaxf(mx, l);
        }
        float s = 0.f;
        #pragma unroll
        for (int d = 0; d < 32; ++d) { lg[d] = __expf(lg[d] - mx); s += lg[d]; }
        const float inv = 1.0f / s;
        #pragma unroll
        for (int d = 0; d < 32; ++d) qk[t][d] = lg[d] * inv;
    }
    __syncthreads();

    float accm[32];
    #pragma unroll
    for (int c = 0; c < 32; ++c) accm[c] = 0.f;
    const float* wvp = wqkv + (long)(512 + h * 32) * 256 + t;
    #pragma unroll 4
    for (int d = 0; d < 32; ++d) {
        const float wvv = wvp[(long)d * 256];
        #pragma unroll
        for (int c = 0; c < 32; ++c) accm[c] += qk[c][d] * wvv;
    }
    float* mo = Mout + (long)b * 256 * 256 + (long)(h * 32) * 256 + t;
    #pragma unroll
    for (int c = 0; c < 32; ++c) mo[(long)c * 256] = accm[c];
}

// ---------------------------------------------------------------------------
// W2[b][g][i] = (softmax(gn_b) . P[b][16g:16g+16][i])
// ---------------------------------------------------------------------------
template <typename OT>
__global__ __launch_bounds__(256) void w2_kernel(
    const float* __restrict__ P, const float* __restrict__ gnb, OT* __restrict__ W2)
{
    const int b = blockIdx.x, i = threadIdx.x;
    float e[16];
    float mx = -1e30f;
    #pragma unroll
    for (int c = 0; c < 16; ++c) mx = fmaxf(mx, gnb[c]);
    float s = 0.f;
    #pragma unroll
    for (int c = 0; c < 16; ++c) { e[c] = __expf(gnb[c] - mx); s += e[c]; }
    const float inv = 1.0f / s;
    const float* Pb = P + (long)b * 256 * 256 + i;
    #pragma unroll
    for (int g = 0; g < 16; ++g) {
        float acc = 0.f;
        #pragma unroll
        for (int c = 0; c < 16; ++c) acc += e[c] * Pb[(long)(g * 16 + c) * 256];
        W2[((long)b * 16 + g) * 256 + i] = (OT)(acc * inv);
    }
}

// ---------------------------------------------------------------------------
// WP[b][g][n] = W2_b[g] . X_b[:,n]  (fallback path only)
// ---------------------------------------------------------------------------
__global__ __launch_bounds__(256) void wpre_kernel(
    const float* __restrict__ W2, const float* __restrict__ X, float* __restrict__ WP)
{
    __shared__ float w2s[16][260];
    const int b = blockIdx.y;
    const int n = blockIdx.x * 256 + threadIdx.x;
    for (int f = threadIdx.x; f < 16 * 64; f += 256) {
        const int g = f >> 6, c4 = f & 63;
        *(float4*)&w2s[g][c4 * 4] = *(const float4*)(W2 + ((long)b * 16 + g) * 256 + c4 * 4);
    }
    __syncthreads();
    float acc[16] = {};
    const float* xb = X + (long)b * 256 * 4096 + n;
    for (int k = 0; k < 256; ++k) {
        const float xv = xb[(long)k * 4096];
        #pragma unroll
        for (int g = 0; g < 16; ++g) acc[g] += w2s[g][k] * xv;
    }
    #pragma unroll
    for (int g = 0; g < 16; ++g) WP[((long)b * 16 + g) * 4096 + n] = acc[g];
}

// ---------------------------------------------------------------------------
extern "C" void kernel_launch(void* const* d_in, const int* in_sizes, int n_in,
                              void* d_out, int out_size, void* d_ws, size_t ws_size,
                              hipStream_t stream)
{
    const float* x     = (const float*)d_in[0];
    const float* gnb   = (const float*)d_in[4];
    const float* wqkv  = (const float*)d_in[5];
    const float* wproj = (const float*)d_in[6];
    const float* temp  = (const float*)d_in[7];
    float* out = (float*)d_out;

    if (ws_size >= 82051072ULL) {
        // Workspace: [Xh 32M][Xt 32M][S1/Mm 4M][pool: T(8M)+Qn(32K) -> {P,Ph,W2h}]
        // Gram split-K partials (32 MB) live in d_out (dead until out_fused).
        char* w = (char*)d_ws;
        _Float16* Xh = (_Float16*)w;
        _Float16* Xt = (_Float16*)(w + 33554432);
        float*    S1 = (float*)(w + 67108864);
        float*    Mm = S1;                          // overlay: attn2 stages S1 in LDS
        char*     pool = w + 71303168;
        float*    T  = (float*)pool;                // 512x256x16 fp32 = 8MB
        float*    Qn = (float*)(pool + 8388608);    // 32KB norms^2
        float*    P  = (float*)pool;                // overwrites dead T
        _Float16* Ph = (_Float16*)(pool + 4194304);
        _Float16* W2h = (_Float16*)(pool + 4194304 + 2097152);
        float*    pG = (float*)d_out;               // scratch: fully overwritten later

        // 1. X -> Xh + Xt (one pass)
        prep_fused<<<dim3(64, 4, 16), 256, 0, stream>>>(x, Xh, Xt);
        // 2. Gram split-K partials into d_out
        gram_split<<<dim3(2, 2, 128), 256, 0, stream>>>(Xh, pG);
        // 3. T = wqkv[0:512] @ (sum_s pG[s])  (reduce fused into B-staging)
        gemm_t8<<<dim3(4, 8, 16), 256, 0, stream>>>(wqkv, pG, T);
        // 4. Qn[b][r] = T[b][r].wqkv[r]
        snorm_kernel<<<2048, 256, 0, stream>>>(T, wqkv, Qn);
        // 5. S1 diag head-blocks = Tq @ Wk^T (only n0==m0 tiles)
        gemm64<true, false, true, false><<<dim3(1, 4, 16), 256, 0, stream>>>(
            T, wqkv + 65536, S1, 256, 256, 256, 131072L, 0L, 65536L,
            nullptr, nullptr, nullptr);
        // 6. softmax + @Wv -> Mm (aliases S1, LDS-staged)
        attn2_kernel<<<128, 256, 0, stream>>>(S1, Qn, wqkv, temp, Mm);
        // 7. P = wproj @ Mm (fp32) + f16 copy Ph (fused cvt)
        gemm64<false, false, false, true><<<dim3(4, 4, 16), 256, 0, stream>>>(
            wproj, Mm, P, 256, 256, 256, 0L, 65536L, 65536L,
            nullptr, nullptr, Ph);
        // 8. W2h = softmax(gn_b)-weighted group sums of P rows (f16)
        w2_kernel<_Float16><<<16, 256, 0, stream>>>(P, gnb, W2h);
        // 9. out = Ph@X + Xh*sigmoid(W2h@X)  (dbuf-pipelined, fused epilogue)
        out_fused<<<dim3(32, 2, 16), 256, 0, stream>>>(Ph, Xt, Xh, W2h, out);
    } else {
        // Fallback: fp32 path (~30 MB workspace)
        float* ws = (float*)d_ws;
        float* G  = ws;
        float* T  = G  + 16L * 65536;
        float* Mm = T  + 16L * 196608;
        float* P  = Mm + 16L * 65536;
        float* W2 = P  + 16L * 65536;
        float* WP = W2 + 16L * 4096;

        gemm64<true, false, false, false><<<dim3(4, 4, 16), 256, 0, stream>>>(
            x, x, G, 256, 256, 4096, 1048576L, 1048576L, 65536L, nullptr, nullptr, nullptr);
        gemm64<false, false, false, false><<<dim3(4, 12, 16), 256, 0, stream>>>(
            wqkv, G, T, 768, 256, 256, 0L, 65536L, 196608L, nullptr, nullptr, nullptr);
        attn_kernel<<<128, 256, 0, stream>>>(T, wqkv, temp, Mm, 196608L);
        gemm64<false, false, false, false><<<dim3(4, 4, 16), 256, 0, stream>>>(
            wproj, Mm, P, 256, 256, 256, 0L, 65536L, 65536L, nullptr, nullptr, nullptr);
        w2_kernel<float><<<16, 256, 0, stream>>>(P, gnb, W2);
        wpre_kernel<<<dim3(16, 16), 256, 0, stream>>>(W2, x, WP);
        gemm64<false, true, false, false><<<dim3(64, 4, 16), 256, 0, stream>>>(
            P, x, out, 256, 4096, 256, 65536L, 1048576L, 1048576L, x, WP, nullptr);
    }
}